// Round 6
// baseline (265.479 us; speedup 1.0000x reference)
//
#include <hip/hip_runtime.h>
#include <math.h>

#define N_NODES 50000
#define N_EDGES 800000
#define IN_FEATS 128
#define N_HIDDEN 128
#define N_CLASSES 40
#define SEQ_LEN 20
#define VOCAB 32000
#define BUCKET_CAP 64     // P(in_deg >= 64 | Poisson(16)) ~ 1e-18; guarded anyway

#define EDGE_BLOCKS 391   // 800000 / (256*8) = 390.6 -> 391, 8 edges/thread
#define POOL_BLOCKS 12500 // 4 nodes per 256-thread block

// prep kernel block ranges
#define ZERO_BLOCKS 49    // 12544 int4 = 200704 B (packed cnt array)
#define W1P_BLOCKS 64     // 16384 packed W1 elements
#define PREP_BLOCKS (ZERO_BLOCKS + W1P_BLOCKS)

#define EGEMM_BLOCKS 500  // 32000 rows / 64 per block

typedef __attribute__((ext_vector_type(8))) short bf16x8;   // 8 bf16 (4 VGPRs)
typedef __attribute__((ext_vector_type(4))) float f32x4;    // MFMA accumulator

#define AS1 __attribute__((address_space(1)))
#define AS3 __attribute__((address_space(3)))

// Direct global->LDS gather: 64 lanes x 4B each, per-lane global source,
// LDS dest = wave-uniform base + lane*4. Zero VGPR cost -> guaranteed MLP.
__device__ __forceinline__ void gld_lds4(const void* g, void* l) {
    __builtin_amdgcn_global_load_lds((const AS1 unsigned int*)g,
                                     (AS3 unsigned int*)l, 4, 0, 0);
}
__device__ __forceinline__ void vm_wait0() {
    asm volatile("s_waitcnt vmcnt(0)" ::: "memory");
}

// bf16 helpers (RNE)
__device__ inline unsigned short f2bf(float x) {
    union { float f; unsigned int u; } v; v.f = x;
    unsigned int r = v.u + 0x7FFF + ((v.u >> 16) & 1);
    return (unsigned short)(r >> 16);
}
__device__ inline float bf2f(unsigned short b) {
    union { float f; unsigned int u; } v; v.u = ((unsigned int)b) << 16;
    return v.f;
}

// ---------------- workspace layout (bytes) ----------------
//   cnt    : 0         int[50000] PACKED: low16 = in-slot/in_deg, high16 = out_deg
//   bucketu: 200704    ushort[50000*64]  6.4 MB (one 128B line per node row)
//   Ep     : 6600704   ushort[32000*128] 8.2 MB (bf16, E' = emb @ W1)
//   G1     : 14792704  ushort[50000*128] 12.8 MB (bf16, pooled E' * rout, folded)
//   G2     : 27592704  ushort[50000*64]  6.4 MB (bf16, stride-64-padded rows)
//   W1p    : 33992704  ushort[128*128]   32 KB (bf16, MFMA-frag-packed)

// ===== prep: zero packed counters ∥ pack W1 into MFMA B-frag layout.
__global__ __launch_bounds__(256) void prep_kernel(
        int4* __restrict__ zero_region, const float* __restrict__ W1,
        unsigned short* __restrict__ W1p) {
    int b = blockIdx.x;
    int t = threadIdx.x;
    if (b < ZERO_BLOCKS) {
        int i = b * 256 + t;
        if (i < 12544) zero_region[i] = make_int4(0, 0, 0, 0);
    } else {
        int i = (b - ZERO_BLOCKS) * 256 + t;  // exactly 16384
        int tile = i >> 9, rem = i & 511;
        int ln = rem >> 3, j = rem & 7;
        int nt = tile >> 2, kb = tile & 3;
        int k = kb * 32 + ((ln >> 4) << 3) + j;
        int n = nt * 16 + (ln & 15);
        W1p[i] = f2bf(W1[k * 128 + n]);
    }
}

// ===== egemm: E' = emb @ W1 via MFMA bf16 (32000x128 @ 128x128).
__global__ __launch_bounds__(256) void egemm_kernel(
        const float* __restrict__ emb, const unsigned short* __restrict__ W1p,
        unsigned short* __restrict__ Ep) {
    const int wave = threadIdx.x >> 6, lane = threadIdx.x & 63;
    const int quad = lane >> 4, m = lane & 15;
    const int row0 = blockIdx.x * 64 + wave * 16;
    const int arow = row0 + m;                       // < 32000 always
    const float4* ap = (const float4*)(emb + arow * 128 + quad * 8);
    bf16x8 a[4];
    #pragma unroll
    for (int kb = 0; kb < 4; ++kb) {                 // k-cols quad*8 + kb*32
        float4 x = ap[kb * 8];
        float4 y = ap[kb * 8 + 1];
        bf16x8 t;
        t[0] = f2bf(x.x); t[1] = f2bf(x.y); t[2] = f2bf(x.z); t[3] = f2bf(x.w);
        t[4] = f2bf(y.x); t[5] = f2bf(y.y); t[6] = f2bf(y.z); t[7] = f2bf(y.w);
        a[kb] = t;
    }
    const int rbase = row0 + quad * 4;
    #pragma unroll
    for (int nt = 0; nt < 8; ++nt) {
        const unsigned short* wp = W1p + (nt * 4) * 512 + lane * 8;
        bf16x8 b0 = *(const bf16x8*)(wp + 0 * 512);
        bf16x8 b1 = *(const bf16x8*)(wp + 1 * 512);
        bf16x8 b2 = *(const bf16x8*)(wp + 2 * 512);
        bf16x8 b3 = *(const bf16x8*)(wp + 3 * 512);
        f32x4 acc = {0.f, 0.f, 0.f, 0.f};
        acc = __builtin_amdgcn_mfma_f32_16x16x32_bf16(a[0], b0, acc, 0, 0, 0);
        acc = __builtin_amdgcn_mfma_f32_16x16x32_bf16(a[1], b1, acc, 0, 0, 0);
        acc = __builtin_amdgcn_mfma_f32_16x16x32_bf16(a[2], b2, acc, 0, 0, 0);
        acc = __builtin_amdgcn_mfma_f32_16x16x32_bf16(a[3], b3, acc, 0, 0, 0);
        #pragma unroll
        for (int r = 0; r < 4; ++r)
            Ep[(rbase + r) * 128 + nt * 16 + m] = f2bf(acc[r]);
    }
}

// ===== R16: edge path ISOLATED (own kernel -> own rocprof row).
// Packed counters: one atomic array, low16 = in-slot claim, high16 = out-deg.
// 8 edges/thread, all 8 in-atomics independent -> 8 outstanding RMWs.
__global__ __launch_bounds__(256) void edge_kernel(
        const int* __restrict__ src, const int* __restrict__ dst,
        unsigned int* __restrict__ cnt, unsigned short* __restrict__ bucketu) {
    int gid = blockIdx.x * 256 + threadIdx.x;
    if (gid >= N_EDGES / 8) return;
    int4 sa = ((const int4*)src)[2 * gid];
    int4 sb = ((const int4*)src)[2 * gid + 1];
    int4 da = ((const int4*)dst)[2 * gid];
    int4 db = ((const int4*)dst)[2 * gid + 1];
    unsigned p0 = atomicAdd(&cnt[da.x], 1u) & 0xffffu;
    unsigned p1 = atomicAdd(&cnt[da.y], 1u) & 0xffffu;
    unsigned p2 = atomicAdd(&cnt[da.z], 1u) & 0xffffu;
    unsigned p3 = atomicAdd(&cnt[da.w], 1u) & 0xffffu;
    unsigned p4 = atomicAdd(&cnt[db.x], 1u) & 0xffffu;
    unsigned p5 = atomicAdd(&cnt[db.y], 1u) & 0xffffu;
    unsigned p6 = atomicAdd(&cnt[db.z], 1u) & 0xffffu;
    unsigned p7 = atomicAdd(&cnt[db.w], 1u) & 0xffffu;
    if (p0 < BUCKET_CAP) bucketu[da.x * BUCKET_CAP + p0] = (unsigned short)sa.x;
    if (p1 < BUCKET_CAP) bucketu[da.y * BUCKET_CAP + p1] = (unsigned short)sa.y;
    if (p2 < BUCKET_CAP) bucketu[da.z * BUCKET_CAP + p2] = (unsigned short)sa.z;
    if (p3 < BUCKET_CAP) bucketu[da.w * BUCKET_CAP + p3] = (unsigned short)sa.w;
    if (p4 < BUCKET_CAP) bucketu[db.x * BUCKET_CAP + p4] = (unsigned short)sb.x;
    if (p5 < BUCKET_CAP) bucketu[db.y * BUCKET_CAP + p5] = (unsigned short)sb.y;
    if (p6 < BUCKET_CAP) bucketu[db.z * BUCKET_CAP + p6] = (unsigned short)sb.z;
    if (p7 < BUCKET_CAP) bucketu[db.w * BUCKET_CAP + p7] = (unsigned short)sb.w;
    atomicAdd(&cnt[sa.x], 0x10000u);
    atomicAdd(&cnt[sa.y], 0x10000u);
    atomicAdd(&cnt[sa.z], 0x10000u);
    atomicAdd(&cnt[sa.w], 0x10000u);
    atomicAdd(&cnt[sb.x], 0x10000u);
    atomicAdd(&cnt[sb.y], 0x10000u);
    atomicAdd(&cnt[sb.z], 0x10000u);
    atomicAdd(&cnt[sb.w], 0x10000u);
}

// ===== R16: pool path ISOLATED; runs after edge_kernel, so out_deg is known
// and rout is folded into the G1 write (scale_g1 kernel deleted).
__global__ __launch_bounds__(256) void pool_kernel(
        const unsigned int* __restrict__ cnt,
        const int* __restrict__ feats, const unsigned short* __restrict__ Ep,
        unsigned short* __restrict__ G1) {
    __shared__ unsigned int pstage[4][SEQ_LEN][64];   // 20480 B
    int t = threadIdx.x;
    int w = t >> 6;
    int v = blockIdx.x * 4 + w;
    int lane = t & 63;

    int toks[SEQ_LEN];
    const int4* tk4 = (const int4*)(feats + v * SEQ_LEN);
    #pragma unroll
    for (int q = 0; q < SEQ_LEN / 4; ++q) {
        int4 tt = tk4[q];
        toks[4 * q + 0] = tt.x;
        toks[4 * q + 1] = tt.y;
        toks[4 * q + 2] = tt.z;
        toks[4 * q + 3] = tt.w;
    }
    int nz = 0;
    #pragma unroll
    for (int s = 0; s < SEQ_LEN; ++s) nz += (toks[s] != 0);

    // issue ALL 20 row-gathers async to LDS (E' row 0 is zero -> pad ok)
    #pragma unroll
    for (int s = 0; s < SEQ_LEN; ++s)
        gld_lds4(Ep + toks[s] * 128 + lane * 2, &pstage[w][s][0]);
    float outd = (float)(cnt[v] >> 16);
    vm_wait0();
    float a0 = 0.f, a1 = 0.f;
    #pragma unroll
    for (int s = 0; s < SEQ_LEN; ++s) {
        unsigned int x = pstage[w][s][lane];
        a0 += bf2f((unsigned short)(x & 0xffffu));
        a1 += bf2f((unsigned short)(x >> 16));
    }
    float sc = rsqrtf(fmaxf(outd, 1.f)) / (float)max(nz, 1);  // rout folded
    ushort2 o = {f2bf(a0 * sc), f2bf(a1 * sc)};
    ((ushort2*)G1)[v * 64 + lane] = o;
}

// ===== spmm1 + gemm2 fused. G1 pre-scaled -> inner loop is pure gather+add.
// All LDS regions wave-private -> no __syncthreads.
__global__ __launch_bounds__(256) void spmm1g2_kernel(
        const unsigned int* __restrict__ cnt,
        const unsigned short* __restrict__ bucketu, const unsigned short* __restrict__ G,
        const float* __restrict__ b1, const float* __restrict__ W2,
        unsigned short* __restrict__ G2) {
    __shared__ unsigned short idxs[256];
    __shared__ float h1s[4][128];
    __shared__ unsigned int stg[4][16][64];    // 16 KB gather stage
    int t = threadIdx.x;
    int node = t >> 6, lane = t & 63;
    int v = blockIdx.x * 4 + node;
    idxs[t] = bucketu[blockIdx.x * 256 + t];   // wave-local row of node `node`
    unsigned c = cnt[v];
    int ind = (int)(c & 0xffffu);
    float outd = (float)(c >> 16);
    float2 bb = ((const float2*)b1)[lane];
    int n = min(ind, BUCKET_CAP);
    const unsigned short* bk = &idxs[node * BUCKET_CAP];
    float a0 = 0.f, a1 = 0.f;
    for (int base = 0; base < n; base += 16) {
        int m = min(16, n - base);
        #pragma unroll 4
        for (int j = 0; j < m; ++j) {
            int u = bk[base + j];
            gld_lds4(G + u * 128 + lane * 2, &stg[node][j][0]);
        }
        vm_wait0();
        #pragma unroll 4
        for (int j = 0; j < m; ++j) {
            unsigned int x = stg[node][j][lane];
            a0 += bf2f((unsigned short)(x & 0xffffu));
            a1 += bf2f((unsigned short)(x >> 16));
        }
    }
    float rin = rsqrtf(fmaxf((float)ind, 1.f));
    float rout = rsqrtf(fmaxf(outd, 1.f));
    h1s[node][2 * lane + 0] = fmaxf(a0 * rin + bb.x, 0.f) * rout;
    h1s[node][2 * lane + 1] = fmaxf(a1 * rin + bb.y, 0.f) * rout;
    // h1s[node] written entirely by this wave -> no barrier needed
    if (lane < N_CLASSES) {
        const float* hn = h1s[node];
        float s0 = 0.f, s1 = 0.f, s2 = 0.f, s3 = 0.f;
        #pragma unroll 8
        for (int k = 0; k < 128; k += 4) {
            s0 += hn[k + 0] * W2[(k + 0) * N_CLASSES + lane];
            s1 += hn[k + 1] * W2[(k + 1) * N_CLASSES + lane];
            s2 += hn[k + 2] * W2[(k + 2) * N_CLASSES + lane];
            s3 += hn[k + 3] * W2[(k + 3) * N_CLASSES + lane];
        }
        G2[v * 64 + lane] = f2bf((s0 + s1) + (s2 + s3));
    }
}

// ===== spmm2: layer-2 aggregate + epilogue. Paired-row direct-to-LDS
// gathers (lanes 0-31 -> row j, lanes 32-63 -> row j+1; 256B per instr).
__global__ __launch_bounds__(256) void spmm2_kernel(
        const unsigned int* __restrict__ cnt, const unsigned short* __restrict__ bucketu,
        const unsigned short* __restrict__ G2, const float* __restrict__ b2,
        float* __restrict__ out) {
    __shared__ unsigned short idxs[256];
    __shared__ unsigned short stg[4][16][64];  // 8 KB
    int t = threadIdx.x;
    int node = t >> 6, f = t & 63;
    int v = blockIdx.x * 4 + node;
    idxs[t] = bucketu[blockIdx.x * 256 + t];   // wave-local
    int ind = (int)(cnt[v] & 0xffffu);
    int n = min(ind, BUCKET_CAP);
    const unsigned short* bk = &idxs[node * BUCKET_CAP];
    int half = f >> 5, sub = f & 31;
    float acc = 0.f;
    for (int base = 0; base < n; base += 16) {
        int m = min(16, n - base);
        #pragma unroll 2
        for (int j = 0; j < m; j += 2) {
            int u0 = bk[base + j];
            int u1 = (j + 1 < m) ? bk[base + j + 1] : u0;
            int u = half ? u1 : u0;
            gld_lds4(G2 + u * 64 + sub * 2, &stg[node][j][0]);
        }
        vm_wait0();
        if (f < N_CLASSES) {
            #pragma unroll 4
            for (int j = 0; j < m; ++j) acc += bf2f(stg[node][j][f]);
        }
    }
    if (f < N_CLASSES) {
        float rin = rsqrtf(fmaxf((float)ind, 1.f));
        out[v * N_CLASSES + f] = acc * rin + b2[f];
    }
}

extern "C" void kernel_launch(void* const* d_in, const int* in_sizes, int n_in,
                              void* d_out, int out_size, void* d_ws, size_t ws_size,
                              hipStream_t stream) {
    const int*   feats = (const int*)d_in[0];
    const int*   src   = (const int*)d_in[1];
    const int*   dst   = (const int*)d_in[2];
    const float* emb   = (const float*)d_in[3];
    const float* W1    = (const float*)d_in[4];
    const float* b1    = (const float*)d_in[5];
    const float* W2    = (const float*)d_in[6];
    const float* b2    = (const float*)d_in[7];
    float* out = (float*)d_out;

    char* w = (char*)d_ws;
    unsigned int*   cnt     = (unsigned int*)(w + 0);
    unsigned short* bucketu = (unsigned short*)(w + 200704);
    unsigned short* Ep      = (unsigned short*)(w + 6600704);
    unsigned short* G1      = (unsigned short*)(w + 14792704);
    unsigned short* G2      = (unsigned short*)(w + 27592704);
    unsigned short* W1p     = (unsigned short*)(w + 33992704);

    // 1) prep: zero packed counters ∥ W1 frag-pack
    prep_kernel<<<PREP_BLOCKS, 256, 0, stream>>>((int4*)w, W1, W1p);
    // 2) E' = emb @ W1 via MFMA
    egemm_kernel<<<EGEMM_BLOCKS, 256, 0, stream>>>(emb, W1p, Ep);
    // 3) edge: bucket-CSC build + packed in/out degree (isolated for profiling)
    edge_kernel<<<EDGE_BLOCKS, 256, 0, stream>>>(src, dst, cnt, bucketu);
    // 4) pool: mean-pool over E' with rout folded -> G1 (scale pass deleted)
    pool_kernel<<<POOL_BLOCKS, 256, 0, stream>>>(cnt, feats, Ep, G1);
    // 5) spmm1 + gemm2 fused -> G2
    spmm1g2_kernel<<<POOL_BLOCKS, 256, 0, stream>>>(cnt, bucketu, G1, b1, W2, G2);
    // 6) out = agg(G2)*rin + b2
    spmm2_kernel<<<POOL_BLOCKS, 256, 0, stream>>>(cnt, bucketu, G2, b2, out);
}

// Round 7
// 242.836 us; speedup vs baseline: 1.0932x; 1.0932x over previous
//
#include <hip/hip_runtime.h>
#include <math.h>

#define N_NODES 50000
#define N_EDGES 800000
#define IN_FEATS 128
#define N_HIDDEN 128
#define N_CLASSES 40
#define SEQ_LEN 20
#define VOCAB 32000
#define BUCKET_CAP 64     // P(in_deg >= 64 | Poisson(16)) ~ 1e-18; guarded anyway

// ---- fused build kernel: b%9==0 -> edge (2 edges/thread), else pool
#define POOL_BLOCKS 12500 // 4 nodes per 256-thread block
#define K1_BLOCKS 14063   // 1563 edge blocks + 12500 pool blocks

// ---- out-degree histogram (atomic-free): 196 partitions of 256 node ids
#define NPART 196
#define PCAP 4608         // per-partition capacity; E[size]=4096, sigma~64 -> +8sigma
#define HSCAT_BLOCKS 196  // x4096 srcs = 802816 >= 800000

// prep: 1 zero block (pcnt) + 64 W1p-pack blocks
#define PREP_BLOCKS 65
#define EGEMM_BLOCKS 500  // 32000 rows / 64 per block

typedef __attribute__((ext_vector_type(8))) short bf16x8;   // 8 bf16 (4 VGPRs)
typedef __attribute__((ext_vector_type(4))) float f32x4;    // MFMA accumulator

#define AS1 __attribute__((address_space(1)))
#define AS3 __attribute__((address_space(3)))

// Direct global->LDS gather: 64 lanes x 4B each, per-lane global source,
// LDS dest = wave-uniform base + lane*4. Zero VGPR cost -> guaranteed MLP.
__device__ __forceinline__ void gld_lds4(const void* g, void* l) {
    __builtin_amdgcn_global_load_lds((const AS1 unsigned int*)g,
                                     (AS3 unsigned int*)l, 4, 0, 0);
}
__device__ __forceinline__ void vm_wait0() {
    asm volatile("s_waitcnt vmcnt(0)" ::: "memory");
}

// bf16 helpers (RNE)
__device__ inline unsigned short f2bf(float x) {
    union { float f; unsigned int u; } v; v.f = x;
    unsigned int r = v.u + 0x7FFF + ((v.u >> 16) & 1);
    return (unsigned short)(r >> 16);
}
__device__ inline float bf2f(unsigned short b) {
    union { float f; unsigned int u; } v; v.u = ((unsigned int)b) << 16;
    return v.f;
}

// ---------------- workspace layout (bytes) ----------------
//   cnt    : 0         uint[50000] PACKED: low16 in-slot/in_deg, high16 out_deg
//                      (fully initialized by hist_count: out<<16, low16=0)
//   pcnt   : 200704    uint[196] partition fill counters (zeroed by prep)
//   bucketu: 201728    ushort[50000*64]  6.4 MB (one 128B line per node row)
//   partbuf: 6601728   uchar[196*4608]   903 KB (src local-ids by partition)
//   Ep     : 7504896   ushort[32000*128] 8.2 MB (bf16, E' = emb @ W1)
//   G1     : 15696896  ushort[50000*128] 12.8 MB (bf16, pooled E' * rout)
//   G2     : 28496896  ushort[50000*64]  6.4 MB (bf16, stride-64-padded rows)
//   W1p    : 34896896  ushort[128*128]   32 KB (bf16, MFMA-frag-packed)

// ===== prep: zero pcnt ∥ pack W1 into MFMA B-frag layout.
__global__ __launch_bounds__(256) void prep_kernel(
        int4* __restrict__ pcnt_zero, const float* __restrict__ W1,
        unsigned short* __restrict__ W1p) {
    int b = blockIdx.x;
    int t = threadIdx.x;
    if (b == 0) {
        if (t < 64) pcnt_zero[t] = make_int4(0, 0, 0, 0);   // 1024 B covers pcnt
    } else {
        int i = (b - 1) * 256 + t;  // exactly 16384
        int tile = i >> 9, rem = i & 511;
        int ln = rem >> 3, j = rem & 7;
        int nt = tile >> 2, kb = tile & 3;
        int k = kb * 32 + ((ln >> 4) << 3) + j;
        int n = nt * 16 + (ln & 15);
        W1p[i] = f2bf(W1[k * 128 + n]);
    }
}

// ===== egemm: E' = emb @ W1 via MFMA bf16 (32000x128 @ 128x128).
__global__ __launch_bounds__(256) void egemm_kernel(
        const float* __restrict__ emb, const unsigned short* __restrict__ W1p,
        unsigned short* __restrict__ Ep) {
    const int wave = threadIdx.x >> 6, lane = threadIdx.x & 63;
    const int quad = lane >> 4, m = lane & 15;
    const int row0 = blockIdx.x * 64 + wave * 16;
    const int arow = row0 + m;                       // < 32000 always
    const float4* ap = (const float4*)(emb + arow * 128 + quad * 8);
    bf16x8 a[4];
    #pragma unroll
    for (int kb = 0; kb < 4; ++kb) {                 // k-cols quad*8 + kb*32
        float4 x = ap[kb * 8];
        float4 y = ap[kb * 8 + 1];
        bf16x8 t;
        t[0] = f2bf(x.x); t[1] = f2bf(x.y); t[2] = f2bf(x.z); t[3] = f2bf(x.w);
        t[4] = f2bf(y.x); t[5] = f2bf(y.y); t[6] = f2bf(y.z); t[7] = f2bf(y.w);
        a[kb] = t;
    }
    const int rbase = row0 + quad * 4;
    #pragma unroll
    for (int nt = 0; nt < 8; ++nt) {
        const unsigned short* wp = W1p + (nt * 4) * 512 + lane * 8;
        bf16x8 b0 = *(const bf16x8*)(wp + 0 * 512);
        bf16x8 b1 = *(const bf16x8*)(wp + 1 * 512);
        bf16x8 b2 = *(const bf16x8*)(wp + 2 * 512);
        bf16x8 b3 = *(const bf16x8*)(wp + 3 * 512);
        f32x4 acc = {0.f, 0.f, 0.f, 0.f};
        acc = __builtin_amdgcn_mfma_f32_16x16x32_bf16(a[0], b0, acc, 0, 0, 0);
        acc = __builtin_amdgcn_mfma_f32_16x16x32_bf16(a[1], b1, acc, 0, 0, 0);
        acc = __builtin_amdgcn_mfma_f32_16x16x32_bf16(a[2], b2, acc, 0, 0, 0);
        acc = __builtin_amdgcn_mfma_f32_16x16x32_bf16(a[3], b3, acc, 0, 0, 0);
        #pragma unroll
        for (int r = 0; r < 4; ++r)
            Ep[(rbase + r) * 128 + nt * 16 + m] = f2bf(acc[r]);
    }
}

// ===== R17 hist pass 1: partition src ids (u>>8) into 196 byte-buffers.
// LDS-ranked scatter: per-edge rank via LDS atomic, ONE global atomic per
// (block,partition) = 38K total (vs 800K out_cnt atomics removed).
__global__ __launch_bounds__(256) void hist_scatter_kernel(
        const int* __restrict__ src, unsigned int* __restrict__ pcnt,
        unsigned char* __restrict__ partbuf) {
    __shared__ unsigned int lhist[NPART];
    __shared__ unsigned int lbase[NPART];
    int t = threadIdx.x;
    for (int i = t; i < NPART; i += 256) lhist[i] = 0u;
    __syncthreads();
    int base = blockIdx.x * 4096;
    int pid[16]; unsigned int rank[16]; unsigned char val[16];
    #pragma unroll
    for (int k = 0; k < 16; ++k) {
        int i = base + k * 256 + t;
        pid[k] = -1;
        if (i < N_EDGES) {
            int u = src[i];
            val[k] = (unsigned char)(u & 255);
            pid[k] = u >> 8;
            rank[k] = atomicAdd(&lhist[pid[k]], 1u);
        }
    }
    __syncthreads();
    for (int i = t; i < NPART; i += 256)
        lbase[i] = atomicAdd(&pcnt[i], lhist[i]);
    __syncthreads();
    #pragma unroll
    for (int k = 0; k < 16; ++k) {
        if (pid[k] >= 0) {
            unsigned int pos = lbase[pid[k]] + rank[k];
            if (pos < PCAP) partbuf[pid[k] * PCAP + pos] = val[k];
        }
    }
}

// ===== R17 hist pass 2: per-partition LDS histogram -> cnt[v] = out_deg<<16.
// Plain stores (exclusive owner). Also zero-inits the low-16 in-slot field,
// so prep no longer zeroes cnt.
__global__ __launch_bounds__(256) void hist_count_kernel(
        const unsigned int* __restrict__ pcnt, const unsigned char* __restrict__ partbuf,
        unsigned int* __restrict__ cnt) {
    __shared__ unsigned int h[256];
    int p = blockIdx.x, t = threadIdx.x;
    h[t] = 0u;
    __syncthreads();
    int n = min((int)pcnt[p], PCAP);
    const unsigned char* pb = partbuf + p * PCAP;
    for (int i = t; i < n; i += 256) atomicAdd(&h[pb[i]], 1u);
    __syncthreads();
    int v = p * 256 + t;
    if (v < N_NODES) cnt[v] = h[t] << 16;
}

// ===== fused build: edge (b%9==0) ∥ pool. Edge keeps ONLY the irreducible
// 800K slot-claim atomics (+1u low16; never carries into out_deg high16).
// Pool reads cnt[v]>>16 (stable during kernel) -> rout folded into G1 write.
__global__ __launch_bounds__(256) void build_kernel(
        const int* __restrict__ src, const int* __restrict__ dst,
        unsigned int* __restrict__ cnt, unsigned short* __restrict__ bucketu,
        const int* __restrict__ feats, const unsigned short* __restrict__ Ep,
        unsigned short* __restrict__ G1) {
    __shared__ unsigned int pstage[4][SEQ_LEN][64];   // 20480 B
    int b = blockIdx.x;
    int t = threadIdx.x;
    if (b % 9 == 0) {
        // ---- edge path: 2 edges/thread, int2 loads, slot-claim atomics only
        int gid = (b / 9) * 256 + t;
        if (gid < N_EDGES / 2) {
            int2 s2 = ((const int2*)src)[gid];
            int2 d2 = ((const int2*)dst)[gid];
            unsigned p0 = atomicAdd(&cnt[d2.x], 1u) & 0xffffu;
            unsigned p1 = atomicAdd(&cnt[d2.y], 1u) & 0xffffu;
            if (p0 < BUCKET_CAP) bucketu[d2.x * BUCKET_CAP + p0] = (unsigned short)s2.x;
            if (p1 < BUCKET_CAP) bucketu[d2.y * BUCKET_CAP + p1] = (unsigned short)s2.y;
        }
    } else {
        // ---- pool path: 4 nodes/block (1 wave each), direct-to-LDS gathers
        int pb = b - b / 9 - 1;
        int w = t >> 6;
        int v = pb * 4 + w;
        int lane = t & 63;

        int toks[SEQ_LEN];
        const int4* tk4 = (const int4*)(feats + v * SEQ_LEN);
        #pragma unroll
        for (int q = 0; q < SEQ_LEN / 4; ++q) {
            int4 tt = tk4[q];
            toks[4 * q + 0] = tt.x;
            toks[4 * q + 1] = tt.y;
            toks[4 * q + 2] = tt.z;
            toks[4 * q + 3] = tt.w;
        }
        int nz = 0;
        #pragma unroll
        for (int s = 0; s < SEQ_LEN; ++s) nz += (toks[s] != 0);

        // issue ALL 20 row-gathers async to LDS (E' row 0 is zero -> pad ok)
        #pragma unroll
        for (int s = 0; s < SEQ_LEN; ++s)
            gld_lds4(Ep + toks[s] * 128 + lane * 2, &pstage[w][s][0]);
        float outd = (float)(cnt[v] >> 16);   // stable high16 (edge adds +1u only)
        vm_wait0();
        float a0 = 0.f, a1 = 0.f;
        #pragma unroll
        for (int s = 0; s < SEQ_LEN; ++s) {
            unsigned int x = pstage[w][s][lane];
            a0 += bf2f((unsigned short)(x & 0xffffu));
            a1 += bf2f((unsigned short)(x >> 16));
        }
        float sc = rsqrtf(fmaxf(outd, 1.f)) / (float)max(nz, 1);  // rout folded
        ushort2 o = {f2bf(a0 * sc), f2bf(a1 * sc)};
        ((ushort2*)G1)[v * 64 + lane] = o;
    }
}

// ===== spmm1 + gemm2 fused. G1 pre-scaled -> inner loop is pure gather+add.
// All LDS regions wave-private -> no __syncthreads.
__global__ __launch_bounds__(256) void spmm1g2_kernel(
        const unsigned int* __restrict__ cnt,
        const unsigned short* __restrict__ bucketu, const unsigned short* __restrict__ G,
        const float* __restrict__ b1, const float* __restrict__ W2,
        unsigned short* __restrict__ G2) {
    __shared__ unsigned short idxs[256];
    __shared__ float h1s[4][128];
    __shared__ unsigned int stg[4][16][64];    // 16 KB gather stage
    int t = threadIdx.x;
    int node = t >> 6, lane = t & 63;
    int v = blockIdx.x * 4 + node;
    idxs[t] = bucketu[blockIdx.x * 256 + t];   // wave-local row of node `node`
    unsigned c = cnt[v];
    int ind = (int)(c & 0xffffu);
    float outd = (float)(c >> 16);
    float2 bb = ((const float2*)b1)[lane];
    int n = min(ind, BUCKET_CAP);
    const unsigned short* bk = &idxs[node * BUCKET_CAP];
    float a0 = 0.f, a1 = 0.f;
    for (int base = 0; base < n; base += 16) {
        int m = min(16, n - base);
        #pragma unroll 4
        for (int j = 0; j < m; ++j) {
            int u = bk[base + j];
            gld_lds4(G + u * 128 + lane * 2, &stg[node][j][0]);
        }
        vm_wait0();
        #pragma unroll 4
        for (int j = 0; j < m; ++j) {
            unsigned int x = stg[node][j][lane];
            a0 += bf2f((unsigned short)(x & 0xffffu));
            a1 += bf2f((unsigned short)(x >> 16));
        }
    }
    float rin = rsqrtf(fmaxf((float)ind, 1.f));
    float rout = rsqrtf(fmaxf(outd, 1.f));
    h1s[node][2 * lane + 0] = fmaxf(a0 * rin + bb.x, 0.f) * rout;
    h1s[node][2 * lane + 1] = fmaxf(a1 * rin + bb.y, 0.f) * rout;
    // h1s[node] written entirely by this wave -> no barrier needed
    if (lane < N_CLASSES) {
        const float* hn = h1s[node];
        float s0 = 0.f, s1 = 0.f, s2 = 0.f, s3 = 0.f;
        #pragma unroll 8
        for (int k = 0; k < 128; k += 4) {
            s0 += hn[k + 0] * W2[(k + 0) * N_CLASSES + lane];
            s1 += hn[k + 1] * W2[(k + 1) * N_CLASSES + lane];
            s2 += hn[k + 2] * W2[(k + 2) * N_CLASSES + lane];
            s3 += hn[k + 3] * W2[(k + 3) * N_CLASSES + lane];
        }
        G2[v * 64 + lane] = f2bf((s0 + s1) + (s2 + s3));
    }
}

// ===== spmm2: layer-2 aggregate + epilogue. Paired-row direct-to-LDS
// gathers (lanes 0-31 -> row j, lanes 32-63 -> row j+1; 256B per instr).
__global__ __launch_bounds__(256) void spmm2_kernel(
        const unsigned int* __restrict__ cnt, const unsigned short* __restrict__ bucketu,
        const unsigned short* __restrict__ G2, const float* __restrict__ b2,
        float* __restrict__ out) {
    __shared__ unsigned short idxs[256];
    __shared__ unsigned short stg[4][16][64];  // 8 KB
    int t = threadIdx.x;
    int node = t >> 6, f = t & 63;
    int v = blockIdx.x * 4 + node;
    idxs[t] = bucketu[blockIdx.x * 256 + t];   // wave-local
    int ind = (int)(cnt[v] & 0xffffu);
    int n = min(ind, BUCKET_CAP);
    const unsigned short* bk = &idxs[node * BUCKET_CAP];
    int half = f >> 5, sub = f & 31;
    float acc = 0.f;
    for (int base = 0; base < n; base += 16) {
        int m = min(16, n - base);
        #pragma unroll 2
        for (int j = 0; j < m; j += 2) {
            int u0 = bk[base + j];
            int u1 = (j + 1 < m) ? bk[base + j + 1] : u0;
            int u = half ? u1 : u0;
            gld_lds4(G2 + u * 64 + sub * 2, &stg[node][j][0]);
        }
        vm_wait0();
        if (f < N_CLASSES) {
            #pragma unroll 4
            for (int j = 0; j < m; ++j) acc += bf2f(stg[node][j][f]);
        }
    }
    if (f < N_CLASSES) {
        float rin = rsqrtf(fmaxf((float)ind, 1.f));
        out[v * N_CLASSES + f] = acc * rin + b2[f];
    }
}

extern "C" void kernel_launch(void* const* d_in, const int* in_sizes, int n_in,
                              void* d_out, int out_size, void* d_ws, size_t ws_size,
                              hipStream_t stream) {
    const int*   feats = (const int*)d_in[0];
    const int*   src   = (const int*)d_in[1];
    const int*   dst   = (const int*)d_in[2];
    const float* emb   = (const float*)d_in[3];
    const float* W1    = (const float*)d_in[4];
    const float* b1    = (const float*)d_in[5];
    const float* W2    = (const float*)d_in[6];
    const float* b2    = (const float*)d_in[7];
    float* out = (float*)d_out;

    char* w = (char*)d_ws;
    unsigned int*   cnt     = (unsigned int*)(w + 0);
    unsigned int*   pcnt    = (unsigned int*)(w + 200704);
    unsigned short* bucketu = (unsigned short*)(w + 201728);
    unsigned char*  partbuf = (unsigned char*)(w + 6601728);
    unsigned short* Ep      = (unsigned short*)(w + 7504896);
    unsigned short* G1      = (unsigned short*)(w + 15696896);
    unsigned short* G2      = (unsigned short*)(w + 28496896);
    unsigned short* W1p     = (unsigned short*)(w + 34896896);

    // 1) prep: zero pcnt ∥ W1 frag-pack
    prep_kernel<<<PREP_BLOCKS, 256, 0, stream>>>((int4*)pcnt, W1, W1p);
    // 2) E' = emb @ W1 via MFMA
    egemm_kernel<<<EGEMM_BLOCKS, 256, 0, stream>>>(emb, W1p, Ep);
    // 3) out-degree histogram, atomic-free (38K vs 800K atomics)
    hist_scatter_kernel<<<HSCAT_BLOCKS, 256, 0, stream>>>(src, pcnt, partbuf);
    hist_count_kernel<<<NPART, 256, 0, stream>>>(pcnt, partbuf, cnt);
    // 4) fused: bucket-CSC build (in-slot atomics only) ∥ pool -> G1
    build_kernel<<<K1_BLOCKS, 256, 0, stream>>>(src, dst, cnt, bucketu, feats, Ep, G1);
    // 5) spmm1 + gemm2 fused -> G2
    spmm1g2_kernel<<<POOL_BLOCKS, 256, 0, stream>>>(cnt, bucketu, G1, b1, W2, G2);
    // 6) out = agg(G2)*rin + b2
    spmm2_kernel<<<POOL_BLOCKS, 256, 0, stream>>>(cnt, bucketu, G2, b2, out);
}

// Round 8
// 200.843 us; speedup vs baseline: 1.3218x; 1.2091x over previous
//
#include <hip/hip_runtime.h>
#include <math.h>

#define N_NODES 50000
#define N_EDGES 800000
#define IN_FEATS 128
#define N_HIDDEN 128
#define N_CLASSES 40
#define SEQ_LEN 20
#define VOCAB 32000
#define BUCKET_CAP 64     // P(in_deg >= 64 | Poisson(16)) ~ 1e-18; guarded anyway

// ---- partitioned scatter (R17-proven, extended to dst): 196 parts x 256 ids
#define NPART 196
#define PCAP 4608         // mean 4096, sigma ~64 -> +8 sigma
#define SCAT_BLOCKS 392   // 196 src + 196 dst, 4096 edges each
#define POOL_BLOCKS 12500
#define SCATPOOL_BLOCKS (SCAT_BLOCKS + POOL_BLOCKS)  // 12892

// prep: 1 zero block (pcnts) + 64 W1p + 24 W2p
#define PREP_BLOCKS 89
#define EGEMM_BLOCKS 500
#define GEMM2_BLOCKS 782  // 50048 rows / 64
#define SCALE_BLOCKS 12500 // 3.2M uints / 256

typedef __attribute__((ext_vector_type(8))) short bf16x8;   // 8 bf16 (4 VGPRs)
typedef __attribute__((ext_vector_type(4))) float f32x4;    // MFMA accumulator

#define AS1 __attribute__((address_space(1)))
#define AS3 __attribute__((address_space(3)))

// Direct global->LDS gather: 64 lanes x 4B, per-lane global src, LDS dest =
// wave-uniform base + lane*4. Zero VGPR cost -> guaranteed deep MLP.
__device__ __forceinline__ void gld_lds4(const void* g, void* l) {
    __builtin_amdgcn_global_load_lds((const AS1 unsigned int*)g,
                                     (AS3 unsigned int*)l, 4, 0, 0);
}
__device__ __forceinline__ void vm_wait0() {
    asm volatile("s_waitcnt vmcnt(0)" ::: "memory");
}

// bf16 helpers (RNE)
__device__ inline unsigned short f2bf(float x) {
    union { float f; unsigned int u; } v; v.f = x;
    unsigned int r = v.u + 0x7FFF + ((v.u >> 16) & 1);
    return (unsigned short)(r >> 16);
}
__device__ inline float bf2f(unsigned short b) {
    union { float f; unsigned int u; } v; v.u = ((unsigned int)b) << 16;
    return v.f;
}

// ---------------- workspace layout (bytes) ----------------
//   cnt    : 0        uint[50000] (out_deg<<16 | in_deg; written by count)
//   pcnt_s : 200704   uint[196]+pad (zeroed by prep)
//   pcnt_d : 201728   uint[196]+pad (zeroed by prep)
//   routf  : 202752   f32[50000] rsqrt(out_deg) (written by count)
//   bucketu: 403456   ushort[50000*64]   6.4 MB
//   -- overlay zone (dead before spmm1): --
//   pbuf_s : 6803456  uchar[196*4608]    903 KB
//   pbuf_d : 7706624  uint[196*4608]     3.6 MB
//   Ep     : 11319296 ushort[32000*128]  8.2 MB
//   h1     : 6803456  ushort[50000*128] 12.8 MB  (OVERLAYS pbuf_s+pbuf_d+Ep)
//   -- end overlay --
//   G1     : 19603456 ushort[50000*128] 12.8 MB
//   G2     : 32403456 ushort[50000*64]   6.4 MB
//   W1p    : 38803456 ushort[128*128]    32 KB
//   W2p    : 38836224 ushort[12*512]     12 KB     (total ~38.85 MB)

// ===== prep: zero both pcnt arrays ∥ pack W1 ∥ pack W2 (MFMA B-frag).
__global__ __launch_bounds__(256) void prep_kernel(
        int4* __restrict__ pcnt_zero, const float* __restrict__ W1,
        unsigned short* __restrict__ W1p, const float* __restrict__ W2,
        unsigned short* __restrict__ W2p) {
    int b = blockIdx.x;
    int t = threadIdx.x;
    if (b == 0) {
        if (t < 128) pcnt_zero[t] = make_int4(0, 0, 0, 0);  // 2048 B = both pcnts
    } else if (b < 65) {
        int i = (b - 1) * 256 + t;  // exactly 16384
        int tile = i >> 9, rem = i & 511;
        int ln = rem >> 3, j = rem & 7;
        int nt = tile >> 2, kb = tile & 3;
        int k = kb * 32 + ((ln >> 4) << 3) + j;
        int n = nt * 16 + (ln & 15);
        W1p[i] = f2bf(W1[k * 128 + n]);
    } else {
        int i = (b - 65) * 256 + t;  // exactly 6144
        int tile = i >> 9, rem = i & 511;
        int ln = rem >> 3, j = rem & 7;
        int nt = tile >> 2, kb = tile & 3;      // nt 0..2
        int k = kb * 32 + ((ln >> 4) << 3) + j;
        int n = nt * 16 + (ln & 15);            // 0..47
        W2p[i] = (n < N_CLASSES) ? f2bf(W2[k * N_CLASSES + n]) : (unsigned short)0;
    }
}

// ===== egemm: E' = emb @ W1 via MFMA bf16 (32000x128 @ 128x128).
__global__ __launch_bounds__(256) void egemm_kernel(
        const float* __restrict__ emb, const unsigned short* __restrict__ W1p,
        unsigned short* __restrict__ Ep) {
    const int wave = threadIdx.x >> 6, lane = threadIdx.x & 63;
    const int quad = lane >> 4, m = lane & 15;
    const int row0 = blockIdx.x * 64 + wave * 16;
    const int arow = row0 + m;                       // < 32000 always
    const float4* ap = (const float4*)(emb + arow * 128 + quad * 8);
    bf16x8 a[4];
    #pragma unroll
    for (int kb = 0; kb < 4; ++kb) {
        float4 x = ap[kb * 8];
        float4 y = ap[kb * 8 + 1];
        bf16x8 t;
        t[0] = f2bf(x.x); t[1] = f2bf(x.y); t[2] = f2bf(x.z); t[3] = f2bf(x.w);
        t[4] = f2bf(y.x); t[5] = f2bf(y.y); t[6] = f2bf(y.z); t[7] = f2bf(y.w);
        a[kb] = t;
    }
    const int rbase = row0 + quad * 4;
    #pragma unroll
    for (int nt = 0; nt < 8; ++nt) {
        const unsigned short* wp = W1p + (nt * 4) * 512 + lane * 8;
        bf16x8 b0 = *(const bf16x8*)(wp + 0 * 512);
        bf16x8 b1 = *(const bf16x8*)(wp + 1 * 512);
        bf16x8 b2 = *(const bf16x8*)(wp + 2 * 512);
        bf16x8 b3 = *(const bf16x8*)(wp + 3 * 512);
        f32x4 acc = {0.f, 0.f, 0.f, 0.f};
        acc = __builtin_amdgcn_mfma_f32_16x16x32_bf16(a[0], b0, acc, 0, 0, 0);
        acc = __builtin_amdgcn_mfma_f32_16x16x32_bf16(a[1], b1, acc, 0, 0, 0);
        acc = __builtin_amdgcn_mfma_f32_16x16x32_bf16(a[2], b2, acc, 0, 0, 0);
        acc = __builtin_amdgcn_mfma_f32_16x16x32_bf16(a[3], b3, acc, 0, 0, 0);
        #pragma unroll
        for (int r = 0; r < 4; ++r)
            Ep[(rbase + r) * 128 + nt * 16 + m] = f2bf(acc[r]);
    }
}

// ===== R18 fused: src-scatter ∥ dst-scatter ∥ pool. ZERO per-edge global
// atomics anywhere (global atomics only for 2x196x196 partition reservations).
__global__ __launch_bounds__(256) void scatpool_kernel(
        const int* __restrict__ src, const int* __restrict__ dst,
        unsigned int* __restrict__ pcnt_s, unsigned char* __restrict__ pbuf_s,
        unsigned int* __restrict__ pcnt_d, unsigned int* __restrict__ pbuf_d,
        const int* __restrict__ feats, const unsigned short* __restrict__ Ep,
        unsigned short* __restrict__ G1) {
    __shared__ unsigned int shm[5120];   // scatter: lhist+lbase; pool: pstage
    int b = blockIdx.x;
    int t = threadIdx.x;
    if (b < 196) {
        // ---- src scatter: partition src ids by u>>8, 1-byte payload (u&255)
        unsigned int* lhist = shm;
        unsigned int* lbase = shm + 256;
        for (int i = t; i < NPART; i += 256) lhist[i] = 0u;
        __syncthreads();
        int base = b * 4096;
        int pid[16]; unsigned int rank[16]; unsigned char val[16];
        #pragma unroll
        for (int k = 0; k < 16; ++k) {
            int i = base + k * 256 + t;
            pid[k] = -1;
            if (i < N_EDGES) {
                int u = src[i];
                val[k] = (unsigned char)(u & 255);
                pid[k] = u >> 8;
                rank[k] = atomicAdd(&lhist[pid[k]], 1u);
            }
        }
        __syncthreads();
        for (int i = t; i < NPART; i += 256)
            lbase[i] = atomicAdd(&pcnt_s[i], lhist[i]);
        __syncthreads();
        #pragma unroll
        for (int k = 0; k < 16; ++k) {
            if (pid[k] >= 0) {
                unsigned int pos = lbase[pid[k]] + rank[k];
                if (pos < PCAP) pbuf_s[pid[k] * PCAP + pos] = val[k];
            }
        }
    } else if (b < 392) {
        // ---- dst scatter: partition by dst>>8, payload (src<<8)|(dst&255)
        unsigned int* lhist = shm;
        unsigned int* lbase = shm + 256;
        for (int i = t; i < NPART; i += 256) lhist[i] = 0u;
        __syncthreads();
        int base = (b - 196) * 4096;
        int pid[16]; unsigned int rank[16]; unsigned int val[16];
        #pragma unroll
        for (int k = 0; k < 16; ++k) {
            int i = base + k * 256 + t;
            pid[k] = -1;
            if (i < N_EDGES) {
                int u = src[i];
                int d = dst[i];
                val[k] = ((unsigned int)u << 8) | (unsigned int)(d & 255);
                pid[k] = d >> 8;
                rank[k] = atomicAdd(&lhist[pid[k]], 1u);
            }
        }
        __syncthreads();
        for (int i = t; i < NPART; i += 256)
            lbase[i] = atomicAdd(&pcnt_d[i], lhist[i]);
        __syncthreads();
        #pragma unroll
        for (int k = 0; k < 16; ++k) {
            if (pid[k] >= 0) {
                unsigned int pos = lbase[pid[k]] + rank[k];
                if (pos < PCAP) pbuf_d[pid[k] * PCAP + pos] = val[k];
            }
        }
    } else {
        // ---- pool: 4 nodes/block, direct-to-LDS gathers; G1 UNSCALED
        unsigned int (*pstage)[SEQ_LEN][64] = (unsigned int (*)[SEQ_LEN][64])shm;
        int pb = b - 392;
        int w = t >> 6;
        int v = pb * 4 + w;
        int lane = t & 63;

        int toks[SEQ_LEN];
        const int4* tk4 = (const int4*)(feats + v * SEQ_LEN);
        #pragma unroll
        for (int q = 0; q < SEQ_LEN / 4; ++q) {
            int4 tt = tk4[q];
            toks[4 * q + 0] = tt.x;
            toks[4 * q + 1] = tt.y;
            toks[4 * q + 2] = tt.z;
            toks[4 * q + 3] = tt.w;
        }
        int nz = 0;
        #pragma unroll
        for (int s = 0; s < SEQ_LEN; ++s) nz += (toks[s] != 0);

        #pragma unroll
        for (int s = 0; s < SEQ_LEN; ++s)
            gld_lds4(Ep + toks[s] * 128 + lane * 2, &pstage[w][s][0]);
        vm_wait0();
        float a0 = 0.f, a1 = 0.f;
        #pragma unroll
        for (int s = 0; s < SEQ_LEN; ++s) {
            unsigned int x = pstage[w][s][lane];
            a0 += bf2f((unsigned short)(x & 0xffffu));
            a1 += bf2f((unsigned short)(x >> 16));
        }
        float sc = 1.f / (float)max(nz, 1);
        ushort2 o = {f2bf(a0 * sc), f2bf(a1 * sc)};
        ((ushort2*)G1)[v * 64 + lane] = o;
    }
}

// ===== count: per partition -> out_deg (src bytes), bucket rows + in_deg
// (dst entries, LDS-rank + plain stores; exclusive 256-node ownership),
// cnt[v] = out<<16|in, routf[v] = rsqrt(out). ZERO global atomics.
__global__ __launch_bounds__(256) void count_kernel(
        const unsigned int* __restrict__ pcnt_s, const unsigned char* __restrict__ pbuf_s,
        const unsigned int* __restrict__ pcnt_d, const unsigned int* __restrict__ pbuf_d,
        unsigned int* __restrict__ cnt, float* __restrict__ routf,
        unsigned short* __restrict__ bucketu) {
    __shared__ unsigned int ho[256];
    __shared__ unsigned int hi_[256];
    int p = blockIdx.x, t = threadIdx.x;
    ho[t] = 0u;
    hi_[t] = 0u;
    __syncthreads();
    int ns = min((int)pcnt_s[p], PCAP);
    const unsigned char* ps = pbuf_s + p * PCAP;
    for (int i = t; i < ns; i += 256) atomicAdd(&ho[ps[i]], 1u);
    int nd = min((int)pcnt_d[p], PCAP);
    const unsigned int* pd = pbuf_d + p * PCAP;
    for (int i = t; i < nd; i += 256) {
        unsigned int e = pd[i];
        unsigned int d = e & 255u;
        unsigned int slot = atomicAdd(&hi_[d], 1u);
        if (slot < BUCKET_CAP)
            bucketu[(p * 256 + (int)d) * BUCKET_CAP + slot] = (unsigned short)(e >> 8);
    }
    __syncthreads();
    int v = p * 256 + t;
    if (v < N_NODES) {
        cnt[v] = (ho[t] << 16) | (hi_[t] & 0xffffu);
        routf[v] = rsqrtf(fmaxf((float)ho[t], 1.f));
    }
}

// ===== scale_g1: G1[row] *= routf[row] in place (fold rout once per row).
__global__ __launch_bounds__(256) void scale_g1_kernel(
        const float* __restrict__ routf, unsigned int* __restrict__ G1u) {
    int i = blockIdx.x * 256 + threadIdx.x;  // 3,200,000 exactly
    int row = i >> 6;
    float ro = routf[row];
    unsigned int x = G1u[i];
    unsigned short lo = f2bf(bf2f((unsigned short)(x & 0xffffu)) * ro);
    unsigned short hi = f2bf(bf2f((unsigned short)(x >> 16)) * ro);
    G1u[i] = (unsigned int)lo | ((unsigned int)hi << 16);
}

// ===== spmm1: pure gather+aggregate -> h1 bf16 (epilogue GEMM extracted).
__global__ __launch_bounds__(256) void spmm1_kernel(
        const unsigned int* __restrict__ cnt, const float* __restrict__ routf,
        const unsigned short* __restrict__ bucketu, const unsigned short* __restrict__ G,
        const float* __restrict__ b1, unsigned short* __restrict__ h1) {
    __shared__ unsigned short idxs[256];
    __shared__ unsigned int stg[4][16][64];    // 16 KB gather stage
    int t = threadIdx.x;
    int node = t >> 6, lane = t & 63;
    int v = blockIdx.x * 4 + node;
    idxs[t] = bucketu[blockIdx.x * 256 + t];
    int ind = (int)(cnt[v] & 0xffffu);
    float rov = routf[v];
    float2 bb = ((const float2*)b1)[lane];
    int n = min(ind, BUCKET_CAP);
    const unsigned short* bk = &idxs[node * BUCKET_CAP];
    float a0 = 0.f, a1 = 0.f;
    for (int base = 0; base < n; base += 16) {
        int m = min(16, n - base);
        #pragma unroll 4
        for (int j = 0; j < m; ++j)
            gld_lds4(G + bk[base + j] * 128 + lane * 2, &stg[node][j][0]);
        vm_wait0();
        #pragma unroll 4
        for (int j = 0; j < m; ++j) {
            unsigned int x = stg[node][j][lane];
            a0 += bf2f((unsigned short)(x & 0xffffu));
            a1 += bf2f((unsigned short)(x >> 16));
        }
    }
    float rin = rsqrtf(fmaxf((float)ind, 1.f));
    float v0 = fmaxf(a0 * rin + bb.x, 0.f) * rov;
    float v1 = fmaxf(a1 * rin + bb.y, 0.f) * rov;
    ushort2 o = {f2bf(v0), f2bf(v1)};
    ((ushort2*)h1)[v * 64 + lane] = o;
}

// ===== gemm2: G2 = h1 @ W2 via MFMA (50048x128 @ 128x48, cols>=40 masked).
__global__ __launch_bounds__(256) void gemm2_kernel(
        const unsigned short* __restrict__ h1, const unsigned short* __restrict__ W2p,
        unsigned short* __restrict__ G2) {
    const int wave = threadIdx.x >> 6, lane = threadIdx.x & 63;
    const int quad = lane >> 4, m = lane & 15;
    const int row0 = blockIdx.x * 64 + wave * 16;
    const int arow = min(row0 + m, N_NODES - 1);
    const unsigned short* ap = h1 + arow * 128 + quad * 8;
    bf16x8 a0 = *(const bf16x8*)(ap + 0);
    bf16x8 a1 = *(const bf16x8*)(ap + 32);
    bf16x8 a2 = *(const bf16x8*)(ap + 64);
    bf16x8 a3 = *(const bf16x8*)(ap + 96);
    const int rbase = row0 + quad * 4;
    #pragma unroll
    for (int nt = 0; nt < 3; ++nt) {
        const unsigned short* wp = W2p + (nt * 4) * 512 + lane * 8;
        bf16x8 b0 = *(const bf16x8*)(wp + 0 * 512);
        bf16x8 b1 = *(const bf16x8*)(wp + 1 * 512);
        bf16x8 b2 = *(const bf16x8*)(wp + 2 * 512);
        bf16x8 b3 = *(const bf16x8*)(wp + 3 * 512);
        f32x4 acc = {0.f, 0.f, 0.f, 0.f};
        acc = __builtin_amdgcn_mfma_f32_16x16x32_bf16(a0, b0, acc, 0, 0, 0);
        acc = __builtin_amdgcn_mfma_f32_16x16x32_bf16(a1, b1, acc, 0, 0, 0);
        acc = __builtin_amdgcn_mfma_f32_16x16x32_bf16(a2, b2, acc, 0, 0, 0);
        acc = __builtin_amdgcn_mfma_f32_16x16x32_bf16(a3, b3, acc, 0, 0, 0);
        int col = nt * 16 + m;
        #pragma unroll
        for (int r = 0; r < 4; ++r) {
            int row = rbase + r;
            if (row < N_NODES && col < N_CLASSES)
                G2[row * 64 + col] = f2bf(acc[r]);
        }
    }
}

// ===== spmm2: layer-2 aggregate + epilogue (paired-row gathers).
__global__ __launch_bounds__(256) void spmm2_kernel(
        const unsigned int* __restrict__ cnt, const unsigned short* __restrict__ bucketu,
        const unsigned short* __restrict__ G2, const float* __restrict__ b2,
        float* __restrict__ out) {
    __shared__ unsigned short idxs[256];
    __shared__ unsigned short stg[4][16][64];  // 8 KB
    int t = threadIdx.x;
    int node = t >> 6, f = t & 63;
    int v = blockIdx.x * 4 + node;
    idxs[t] = bucketu[blockIdx.x * 256 + t];
    int ind = (int)(cnt[v] & 0xffffu);
    int n = min(ind, BUCKET_CAP);
    const unsigned short* bk = &idxs[node * BUCKET_CAP];
    int half = f >> 5, sub = f & 31;
    float acc = 0.f;
    for (int base = 0; base < n; base += 16) {
        int m = min(16, n - base);
        #pragma unroll 2
        for (int j = 0; j < m; j += 2) {
            int u0 = bk[base + j];
            int u1 = (j + 1 < m) ? bk[base + j + 1] : u0;
            int u = half ? u1 : u0;
            gld_lds4(G2 + u * 64 + sub * 2, &stg[node][j][0]);
        }
        vm_wait0();
        if (f < N_CLASSES) {
            #pragma unroll 4
            for (int j = 0; j < m; ++j) acc += bf2f(stg[node][j][f]);
        }
    }
    if (f < N_CLASSES) {
        float rin = rsqrtf(fmaxf((float)ind, 1.f));
        out[v * N_CLASSES + f] = acc * rin + b2[f];
    }
}

extern "C" void kernel_launch(void* const* d_in, const int* in_sizes, int n_in,
                              void* d_out, int out_size, void* d_ws, size_t ws_size,
                              hipStream_t stream) {
    const int*   feats = (const int*)d_in[0];
    const int*   src   = (const int*)d_in[1];
    const int*   dst   = (const int*)d_in[2];
    const float* emb   = (const float*)d_in[3];
    const float* W1    = (const float*)d_in[4];
    const float* b1    = (const float*)d_in[5];
    const float* W2    = (const float*)d_in[6];
    const float* b2    = (const float*)d_in[7];
    float* out = (float*)d_out;

    char* w = (char*)d_ws;
    unsigned int*   cnt     = (unsigned int*)(w + 0);
    unsigned int*   pcnt_s  = (unsigned int*)(w + 200704);
    unsigned int*   pcnt_d  = (unsigned int*)(w + 201728);
    float*          routf   = (float*)(w + 202752);
    unsigned short* bucketu = (unsigned short*)(w + 403456);
    unsigned char*  pbuf_s  = (unsigned char*)(w + 6803456);
    unsigned int*   pbuf_d  = (unsigned int*)(w + 7706624);
    unsigned short* Ep      = (unsigned short*)(w + 11319296);
    unsigned short* h1      = (unsigned short*)(w + 6803456);   // overlay (dead zone)
    unsigned short* G1      = (unsigned short*)(w + 19603456);
    unsigned short* G2      = (unsigned short*)(w + 32403456);
    unsigned short* W1p     = (unsigned short*)(w + 38803456);
    unsigned short* W2p     = (unsigned short*)(w + 38836224);

    // 1) prep: zero pcnts ∥ pack W1 ∥ pack W2
    prep_kernel<<<PREP_BLOCKS, 256, 0, stream>>>(
        (int4*)pcnt_s, W1, W1p, W2, W2p);
    // 2) E' = emb @ W1 via MFMA
    egemm_kernel<<<EGEMM_BLOCKS, 256, 0, stream>>>(emb, W1p, Ep);
    // 3) src-scatter ∥ dst-scatter ∥ pool -> G1 (unscaled); no edge atomics
    scatpool_kernel<<<SCATPOOL_BLOCKS, 256, 0, stream>>>(
        src, dst, pcnt_s, pbuf_s, pcnt_d, pbuf_d, feats, Ep, G1);
    // 4) count: buckets (LDS-rank, plain stores) + cnt + routf
    count_kernel<<<NPART, 256, 0, stream>>>(
        pcnt_s, pbuf_s, pcnt_d, pbuf_d, cnt, routf, bucketu);
    // 5) G1 *= routf (in place)
    scale_g1_kernel<<<SCALE_BLOCKS, 256, 0, stream>>>(routf, (unsigned int*)G1);
    // 6) spmm1: aggregate -> h1 bf16 (overlays dead pbuf/Ep zone)
    spmm1_kernel<<<POOL_BLOCKS, 256, 0, stream>>>(cnt, routf, bucketu, G1, b1, h1);
    // 7) G2 = h1 @ W2 via MFMA
    gemm2_kernel<<<GEMM2_BLOCKS, 256, 0, stream>>>(h1, W2p, G2);
    // 8) out = agg(G2)*rin + b2
    spmm2_kernel<<<POOL_BLOCKS, 256, 0, stream>>>(cnt, bucketu, G2, b2, out);
}

// Round 9
// 190.795 us; speedup vs baseline: 1.3914x; 1.0527x over previous
//
#include <hip/hip_runtime.h>
#include <math.h>

#define N_NODES 50000
#define N_EDGES 800000
#define IN_FEATS 128
#define N_HIDDEN 128
#define N_CLASSES 40
#define SEQ_LEN 20
#define VOCAB 32000
#define BUCKET_CAP 64     // P(in_deg >= 64 | Poisson(16)) ~ 1e-18; guarded anyway

#define NPART 196
#define PCAP 4608         // mean 4096, sigma ~64 -> +8 sigma
// egemm_scat: blocks 0-195 src-scatter, 196-391 dst-scatter, 392-891 egemm
#define EGS_BLOCKS 892
#define POOL_BLOCKS 12500
#define PREP_BLOCKS 89    // 1 zero + 64 W1p + 24 W2p
#define GEMM2_BLOCKS 782  // 50048 rows / 64

typedef __attribute__((ext_vector_type(8))) short bf16x8;   // 8 bf16 (4 VGPRs)
typedef __attribute__((ext_vector_type(4))) float f32x4;    // MFMA accumulator

#define AS1 __attribute__((address_space(1)))
#define AS3 __attribute__((address_space(3)))

// Direct global->LDS: per-lane global src, LDS dest = uniform base + lane*size.
// size=16 (dwordx4): one instruction gathers 1KB -> 4x256B rows or 8x128B rows.
__device__ __forceinline__ void gld_lds16(const void* g, void* l) {
    __builtin_amdgcn_global_load_lds((const AS1 unsigned int*)g,
                                     (AS3 unsigned int*)l, 16, 0, 0);
}
__device__ __forceinline__ void vm_wait0() {
    asm volatile("s_waitcnt vmcnt(0)" ::: "memory");
}

// bf16 helpers (RNE)
__device__ inline unsigned short f2bf(float x) {
    union { float f; unsigned int u; } v; v.f = x;
    unsigned int r = v.u + 0x7FFF + ((v.u >> 16) & 1);
    return (unsigned short)(r >> 16);
}
__device__ inline float bf2f(unsigned short b) {
    union { float f; unsigned int u; } v; v.u = ((unsigned int)b) << 16;
    return v.f;
}

// ---------------- workspace layout (bytes) ----------------
//   cnt    : 0        uint[50000] (out_deg<<16 | in_deg; written by count)
//   pcnt_s : 200704   uint[196]+pad (zeroed by prep)
//   pcnt_d : 201728   uint[196]+pad (zeroed by prep)
//   routf  : 202752   f32[50000] rsqrt(out_deg) (written by count)
//   bucketu: 403456   ushort[50000*64]   6.4 MB
//   -- overlay zone (dead before spmm1): --
//   pbuf_s : 6803456  uchar[196*4608]    903 KB
//   pbuf_d : 7706624  uint[196*4608]     3.6 MB
//   Ep     : 11319296 ushort[32000*128]  8.2 MB
//   h1     : 6803456  ushort[50000*128] 12.8 MB  (OVERLAYS pbuf_s+pbuf_d+Ep)
//   -- end overlay --
//   G1     : 19603456 ushort[50000*128] 12.8 MB
//   G2     : 32403456 ushort[50000*64]   6.4 MB
//   W1p    : 38803456 ushort[128*128]    32 KB
//   W2p    : 38836224 ushort[12*512]     12 KB

// ===== prep: zero both pcnt arrays ∥ pack W1 ∥ pack W2 (MFMA B-frag).
__global__ __launch_bounds__(256) void prep_kernel(
        int4* __restrict__ pcnt_zero, const float* __restrict__ W1,
        unsigned short* __restrict__ W1p, const float* __restrict__ W2,
        unsigned short* __restrict__ W2p) {
    int b = blockIdx.x;
    int t = threadIdx.x;
    if (b == 0) {
        if (t < 128) pcnt_zero[t] = make_int4(0, 0, 0, 0);  // 2048 B = both pcnts
    } else if (b < 65) {
        int i = (b - 1) * 256 + t;  // exactly 16384
        int tile = i >> 9, rem = i & 511;
        int ln = rem >> 3, j = rem & 7;
        int nt = tile >> 2, kb = tile & 3;
        int k = kb * 32 + ((ln >> 4) << 3) + j;
        int n = nt * 16 + (ln & 15);
        W1p[i] = f2bf(W1[k * 128 + n]);
    } else {
        int i = (b - 65) * 256 + t;  // exactly 6144
        int tile = i >> 9, rem = i & 511;
        int ln = rem >> 3, j = rem & 7;
        int nt = tile >> 2, kb = tile & 3;      // nt 0..2
        int k = kb * 32 + ((ln >> 4) << 3) + j;
        int n = nt * 16 + (ln & 15);            // 0..47
        W2p[i] = (n < N_CLASSES) ? f2bf(W2[k * N_CLASSES + n]) : (unsigned short)0;
    }
}

// ===== R19 fused: src-scatter ∥ dst-scatter ∥ egemm (scatter hides under
// the MFMA GEMM; neither depends on the other).
__global__ __launch_bounds__(256) void egemm_scat_kernel(
        const int* __restrict__ src, const int* __restrict__ dst,
        unsigned int* __restrict__ pcnt_s, unsigned char* __restrict__ pbuf_s,
        unsigned int* __restrict__ pcnt_d, unsigned int* __restrict__ pbuf_d,
        const float* __restrict__ emb, const unsigned short* __restrict__ W1p,
        unsigned short* __restrict__ Ep) {
    __shared__ unsigned int shm[512];
    int b = blockIdx.x;
    int t = threadIdx.x;
    if (b < 196) {
        // ---- src scatter: partition src ids by u>>8, 1-byte payload (u&255)
        unsigned int* lhist = shm;
        unsigned int* lbase = shm + 256;
        for (int i = t; i < NPART; i += 256) lhist[i] = 0u;
        __syncthreads();
        int base = b * 4096;
        int pid[16]; unsigned int rank[16]; unsigned char val[16];
        #pragma unroll
        for (int k = 0; k < 16; ++k) {
            int i = base + k * 256 + t;
            pid[k] = -1;
            if (i < N_EDGES) {
                int u = src[i];
                val[k] = (unsigned char)(u & 255);
                pid[k] = u >> 8;
                rank[k] = atomicAdd(&lhist[pid[k]], 1u);
            }
        }
        __syncthreads();
        for (int i = t; i < NPART; i += 256)
            lbase[i] = atomicAdd(&pcnt_s[i], lhist[i]);
        __syncthreads();
        #pragma unroll
        for (int k = 0; k < 16; ++k) {
            if (pid[k] >= 0) {
                unsigned int pos = lbase[pid[k]] + rank[k];
                if (pos < PCAP) pbuf_s[pid[k] * PCAP + pos] = val[k];
            }
        }
    } else if (b < 392) {
        // ---- dst scatter: partition by dst>>8, payload (src<<8)|(dst&255)
        unsigned int* lhist = shm;
        unsigned int* lbase = shm + 256;
        for (int i = t; i < NPART; i += 256) lhist[i] = 0u;
        __syncthreads();
        int base = (b - 196) * 4096;
        int pid[16]; unsigned int rank[16]; unsigned int val[16];
        #pragma unroll
        for (int k = 0; k < 16; ++k) {
            int i = base + k * 256 + t;
            pid[k] = -1;
            if (i < N_EDGES) {
                int u = src[i];
                int d = dst[i];
                val[k] = ((unsigned int)u << 8) | (unsigned int)(d & 255);
                pid[k] = d >> 8;
                rank[k] = atomicAdd(&lhist[pid[k]], 1u);
            }
        }
        __syncthreads();
        for (int i = t; i < NPART; i += 256)
            lbase[i] = atomicAdd(&pcnt_d[i], lhist[i]);
        __syncthreads();
        #pragma unroll
        for (int k = 0; k < 16; ++k) {
            if (pid[k] >= 0) {
                unsigned int pos = lbase[pid[k]] + rank[k];
                if (pos < PCAP) pbuf_d[pid[k] * PCAP + pos] = val[k];
            }
        }
    } else {
        // ---- egemm: E' = emb @ W1 via MFMA (rows (b-392)*64 .. +63)
        const int wave = t >> 6, lane = t & 63;
        const int quad = lane >> 4, m = lane & 15;
        const int row0 = (b - 392) * 64 + wave * 16;
        const int arow = row0 + m;                       // < 32000 always
        const float4* ap = (const float4*)(emb + arow * 128 + quad * 8);
        bf16x8 a[4];
        #pragma unroll
        for (int kb = 0; kb < 4; ++kb) {
            float4 x = ap[kb * 8];
            float4 y = ap[kb * 8 + 1];
            bf16x8 tt;
            tt[0] = f2bf(x.x); tt[1] = f2bf(x.y); tt[2] = f2bf(x.z); tt[3] = f2bf(x.w);
            tt[4] = f2bf(y.x); tt[5] = f2bf(y.y); tt[6] = f2bf(y.z); tt[7] = f2bf(y.w);
            a[kb] = tt;
        }
        const int rbase = row0 + quad * 4;
        #pragma unroll
        for (int nt = 0; nt < 8; ++nt) {
            const unsigned short* wp = W1p + (nt * 4) * 512 + lane * 8;
            bf16x8 b0 = *(const bf16x8*)(wp + 0 * 512);
            bf16x8 b1 = *(const bf16x8*)(wp + 1 * 512);
            bf16x8 b2 = *(const bf16x8*)(wp + 2 * 512);
            bf16x8 b3 = *(const bf16x8*)(wp + 3 * 512);
            f32x4 acc = {0.f, 0.f, 0.f, 0.f};
            acc = __builtin_amdgcn_mfma_f32_16x16x32_bf16(a[0], b0, acc, 0, 0, 0);
            acc = __builtin_amdgcn_mfma_f32_16x16x32_bf16(a[1], b1, acc, 0, 0, 0);
            acc = __builtin_amdgcn_mfma_f32_16x16x32_bf16(a[2], b2, acc, 0, 0, 0);
            acc = __builtin_amdgcn_mfma_f32_16x16x32_bf16(a[3], b3, acc, 0, 0, 0);
            #pragma unroll
            for (int r = 0; r < 4; ++r)
                Ep[(rbase + r) * 128 + nt * 16 + m] = f2bf(acc[r]);
        }
    }
}

// ===== count: per partition -> out_deg, bucket rows + in_deg (LDS-rank,
// plain stores; exclusive 256-node ownership). ZERO global atomics.
__global__ __launch_bounds__(256) void count_kernel(
        const unsigned int* __restrict__ pcnt_s, const unsigned char* __restrict__ pbuf_s,
        const unsigned int* __restrict__ pcnt_d, const unsigned int* __restrict__ pbuf_d,
        unsigned int* __restrict__ cnt, float* __restrict__ routf,
        unsigned short* __restrict__ bucketu) {
    __shared__ unsigned int ho[256];
    __shared__ unsigned int hi_[256];
    int p = blockIdx.x, t = threadIdx.x;
    ho[t] = 0u;
    hi_[t] = 0u;
    __syncthreads();
    int ns = min((int)pcnt_s[p], PCAP);
    const unsigned char* ps = pbuf_s + p * PCAP;
    for (int i = t; i < ns; i += 256) atomicAdd(&ho[ps[i]], 1u);
    int nd = min((int)pcnt_d[p], PCAP);
    const unsigned int* pd = pbuf_d + p * PCAP;
    for (int i = t; i < nd; i += 256) {
        unsigned int e = pd[i];
        unsigned int d = e & 255u;
        unsigned int slot = atomicAdd(&hi_[d], 1u);
        if (slot < BUCKET_CAP)
            bucketu[(p * 256 + (int)d) * BUCKET_CAP + slot] = (unsigned short)(e >> 8);
    }
    __syncthreads();
    int v = p * 256 + t;
    if (v < N_NODES) {
        cnt[v] = (ho[t] << 16) | (hi_[t] & 0xffffu);
        routf[v] = rsqrtf(fmaxf((float)ho[t], 1.f));
    }
}

// ===== pool (runs AFTER count -> rout folded at the single write; scale
// kernel deleted). R19: size=16 gathers -> 5 instructions fetch all 20 rows.
__global__ __launch_bounds__(256) void pool_kernel(
        const float* __restrict__ routf, const int* __restrict__ feats,
        const unsigned short* __restrict__ Ep, unsigned short* __restrict__ G1) {
    __shared__ unsigned int pstage[4][SEQ_LEN][64];   // 20 KB
    __shared__ int tokl[4][SEQ_LEN];
    int t = threadIdx.x;
    int w = t >> 6, lane = t & 63;
    int v = blockIdx.x * 4 + w;
    int mytok = 0;
    if (lane < SEQ_LEN) {
        mytok = feats[v * SEQ_LEN + lane];
        tokl[w][lane] = mytok;
    }
    int nz = (int)__popcll(__ballot(lane < SEQ_LEN && mytok != 0));
    __syncthreads();
    // 5 gathers x 4 rows (16 lanes/row, 16B/lane). E' row 0 = 0 -> pad ok.
    #pragma unroll
    for (int g = 0; g < SEQ_LEN / 4; ++g) {
        int tok = tokl[w][4 * g + (lane >> 4)];
        gld_lds16(Ep + tok * 128 + (lane & 15) * 8, &pstage[w][4 * g][0]);
    }
    float ro = routf[v];
    vm_wait0();
    float a0 = 0.f, a1 = 0.f;
    #pragma unroll
    for (int s = 0; s < SEQ_LEN; ++s) {
        unsigned int x = pstage[w][s][lane];
        a0 += bf2f((unsigned short)(x & 0xffffu));
        a1 += bf2f((unsigned short)(x >> 16));
    }
    float sc = ro / (float)max(nz, 1);     // rout folded, single bf16 rounding
    ushort2 o = {f2bf(a0 * sc), f2bf(a1 * sc)};
    ((ushort2*)G1)[v * 64 + lane] = o;
}

// ===== spmm1: gather+aggregate -> h1. R19: 4 rows per gld instruction,
// 32-row batches (single wait covers deg<=32 ~ 98% of nodes).
__global__ __launch_bounds__(256) void spmm1_kernel(
        const unsigned int* __restrict__ cnt, const float* __restrict__ routf,
        const unsigned short* __restrict__ bucketu, const unsigned short* __restrict__ G,
        const float* __restrict__ b1, unsigned short* __restrict__ h1) {
    __shared__ unsigned short idxs[256];
    __shared__ unsigned int stg[4][32][64];    // 32 KB gather stage
    int t = threadIdx.x;
    int node = t >> 6, lane = t & 63;
    int v = blockIdx.x * 4 + node;
    idxs[t] = bucketu[blockIdx.x * 256 + t];   // wave-local slice
    int ind = (int)(cnt[v] & 0xffffu);
    float rov = routf[v];
    float2 bb = ((const float2*)b1)[lane];
    int n = min(ind, BUCKET_CAP);
    float a0 = 0.f, a1 = 0.f;
    for (int base = 0; base < n; base += 32) {
        int m = min(32, n - base);
        int nin = (m + 3) >> 2;
        for (int g = 0; g < nin; ++g) {
            int rc = min(base + 4 * g + (lane >> 4), n - 1);  // clamp partials
            int u = idxs[node * 64 + rc];
            gld_lds16(G + u * 128 + (lane & 15) * 8, &stg[node][4 * g][0]);
        }
        vm_wait0();
        #pragma unroll 4
        for (int j = 0; j < m; ++j) {
            unsigned int x = stg[node][j][lane];
            a0 += bf2f((unsigned short)(x & 0xffffu));
            a1 += bf2f((unsigned short)(x >> 16));
        }
    }
    float rin = rsqrtf(fmaxf((float)ind, 1.f));
    float v0 = fmaxf(a0 * rin + bb.x, 0.f) * rov;
    float v1 = fmaxf(a1 * rin + bb.y, 0.f) * rov;
    ushort2 o = {f2bf(v0), f2bf(v1)};
    ((ushort2*)h1)[v * 64 + lane] = o;
}

// ===== gemm2: G2 = h1 @ W2 via MFMA (50048x128 @ 128x48, cols>=40 masked).
__global__ __launch_bounds__(256) void gemm2_kernel(
        const unsigned short* __restrict__ h1, const unsigned short* __restrict__ W2p,
        unsigned short* __restrict__ G2) {
    const int wave = threadIdx.x >> 6, lane = threadIdx.x & 63;
    const int quad = lane >> 4, m = lane & 15;
    const int row0 = blockIdx.x * 64 + wave * 16;
    const int arow = min(row0 + m, N_NODES - 1);
    const unsigned short* ap = h1 + arow * 128 + quad * 8;
    bf16x8 a0 = *(const bf16x8*)(ap + 0);
    bf16x8 a1 = *(const bf16x8*)(ap + 32);
    bf16x8 a2 = *(const bf16x8*)(ap + 64);
    bf16x8 a3 = *(const bf16x8*)(ap + 96);
    const int rbase = row0 + quad * 4;
    #pragma unroll
    for (int nt = 0; nt < 3; ++nt) {
        const unsigned short* wp = W2p + (nt * 4) * 512 + lane * 8;
        bf16x8 b0 = *(const bf16x8*)(wp + 0 * 512);
        bf16x8 b1 = *(const bf16x8*)(wp + 1 * 512);
        bf16x8 b2 = *(const bf16x8*)(wp + 2 * 512);
        bf16x8 b3 = *(const bf16x8*)(wp + 3 * 512);
        f32x4 acc = {0.f, 0.f, 0.f, 0.f};
        acc = __builtin_amdgcn_mfma_f32_16x16x32_bf16(a0, b0, acc, 0, 0, 0);
        acc = __builtin_amdgcn_mfma_f32_16x16x32_bf16(a1, b1, acc, 0, 0, 0);
        acc = __builtin_amdgcn_mfma_f32_16x16x32_bf16(a2, b2, acc, 0, 0, 0);
        acc = __builtin_amdgcn_mfma_f32_16x16x32_bf16(a3, b3, acc, 0, 0, 0);
        int col = nt * 16 + m;
        #pragma unroll
        for (int r = 0; r < 4; ++r) {
            int row = rbase + r;
            if (row < N_NODES && col < N_CLASSES)
                G2[row * 64 + col] = f2bf(acc[r]);
        }
    }
}

// ===== spmm2: layer-2 aggregate + epilogue. R19: 8 rows per gld instruction
// (8 lanes/row x 16B), 32-row batches -> deg<=32 = one wait, 4 instructions.
__global__ __launch_bounds__(256) void spmm2_kernel(
        const unsigned int* __restrict__ cnt, const unsigned short* __restrict__ bucketu,
        const unsigned short* __restrict__ G2, const float* __restrict__ b2,
        float* __restrict__ out) {
    __shared__ unsigned short idxs[256];
    __shared__ unsigned short stg[4][32][64];  // 16 KB; row stride 128B
    int t = threadIdx.x;
    int node = t >> 6, f = t & 63;
    int v = blockIdx.x * 4 + node;
    idxs[t] = bucketu[blockIdx.x * 256 + t];
    int ind = (int)(cnt[v] & 0xffffu);
    int n = min(ind, BUCKET_CAP);
    float acc = 0.f;
    for (int base = 0; base < n; base += 32) {
        int m = min(32, n - base);
        int nin = (m + 7) >> 3;
        for (int g = 0; g < nin; ++g) {
            int rc = min(base + 8 * g + (f >> 3), n - 1);   // clamp partials
            int u = idxs[node * 64 + rc];
            gld_lds16(G2 + u * 64 + (f & 7) * 8, &stg[node][8 * g][0]);
        }
        vm_wait0();
        if (f < N_CLASSES) {
            #pragma unroll 4
            for (int j = 0; j < m; ++j) acc += bf2f(stg[node][j][f]);
        }
    }
    if (f < N_CLASSES) {
        float rin = rsqrtf(fmaxf((float)ind, 1.f));
        out[v * N_CLASSES + f] = acc * rin + b2[f];
    }
}

extern "C" void kernel_launch(void* const* d_in, const int* in_sizes, int n_in,
                              void* d_out, int out_size, void* d_ws, size_t ws_size,
                              hipStream_t stream) {
    const int*   feats = (const int*)d_in[0];
    const int*   src   = (const int*)d_in[1];
    const int*   dst   = (const int*)d_in[2];
    const float* emb   = (const float*)d_in[3];
    const float* W1    = (const float*)d_in[4];
    const float* b1    = (const float*)d_in[5];
    const float* W2    = (const float*)d_in[6];
    const float* b2    = (const float*)d_in[7];
    float* out = (float*)d_out;

    char* w = (char*)d_ws;
    unsigned int*   cnt     = (unsigned int*)(w + 0);
    unsigned int*   pcnt_s  = (unsigned int*)(w + 200704);
    unsigned int*   pcnt_d  = (unsigned int*)(w + 201728);
    float*          routf   = (float*)(w + 202752);
    unsigned short* bucketu = (unsigned short*)(w + 403456);
    unsigned char*  pbuf_s  = (unsigned char*)(w + 6803456);
    unsigned int*   pbuf_d  = (unsigned int*)(w + 7706624);
    unsigned short* Ep      = (unsigned short*)(w + 11319296);
    unsigned short* h1      = (unsigned short*)(w + 6803456);   // overlay (dead zone)
    unsigned short* G1      = (unsigned short*)(w + 19603456);
    unsigned short* G2      = (unsigned short*)(w + 32403456);
    unsigned short* W1p     = (unsigned short*)(w + 38803456);
    unsigned short* W2p     = (unsigned short*)(w + 38836224);

    // 1) prep: zero pcnts ∥ pack W1 ∥ pack W2
    prep_kernel<<<PREP_BLOCKS, 256, 0, stream>>>((int4*)pcnt_s, W1, W1p, W2, W2p);
    // 2) src/dst scatter ∥ egemm (independent; scatter hides under MFMA)
    egemm_scat_kernel<<<EGS_BLOCKS, 256, 0, stream>>>(
        src, dst, pcnt_s, pbuf_s, pcnt_d, pbuf_d, emb, W1p, Ep);
    // 3) count: buckets + cnt + routf (zero global atomics)
    count_kernel<<<NPART, 256, 0, stream>>>(
        pcnt_s, pbuf_s, pcnt_d, pbuf_d, cnt, routf, bucketu);
    // 4) pool -> G1 (rout folded; 5 gather instructions per node)
    pool_kernel<<<POOL_BLOCKS, 256, 0, stream>>>(routf, feats, Ep, G1);
    // 5) spmm1: aggregate -> h1
    spmm1_kernel<<<POOL_BLOCKS, 256, 0, stream>>>(cnt, routf, bucketu, G1, b1, h1);
    // 6) G2 = h1 @ W2 via MFMA
    gemm2_kernel<<<GEMM2_BLOCKS, 256, 0, stream>>>(h1, W2p, G2);
    // 7) out = agg(G2)*rin + b2
    spmm2_kernel<<<POOL_BLOCKS, 256, 0, stream>>>(cnt, bucketu, G2, b2, out);
}

// Round 10
// 184.964 us; speedup vs baseline: 1.4353x; 1.0315x over previous
//
#include <hip/hip_runtime.h>
#include <math.h>

#define N_NODES 50000
#define N_EDGES 800000
#define IN_FEATS 128
#define N_HIDDEN 128
#define N_CLASSES 40
#define SEQ_LEN 20
#define VOCAB 32000
#define BUCKET_CAP 64     // P(in_deg >= 64 | Poisson(16)) ~ 1e-18; guarded anyway

#define NPART 196
#define PCAP 4608         // mean 4096, sigma ~64 -> +8 sigma
// egemm_scat: blocks 0-195 src-scatter, 196-391 dst-scatter, 392-891 egemm
#define EGS_BLOCKS 892
#define POOL_BLOCKS 12500
// poolcount: blocks 0-195 = count (hidden under pool), 196.. = pool
#define POOLCOUNT_BLOCKS (NPART + POOL_BLOCKS)   // 12696
#define PREP_BLOCKS 89    // 1 zero + 64 W1p + 24 W2p
#define GEMM2_BLOCKS 782  // 50048 rows / 64

typedef __attribute__((ext_vector_type(8))) short bf16x8;   // 8 bf16 (4 VGPRs)
typedef __attribute__((ext_vector_type(4))) float f32x4;    // MFMA accumulator

#define AS1 __attribute__((address_space(1)))
#define AS3 __attribute__((address_space(3)))

// Direct global->LDS: per-lane global src, LDS dest = uniform base + lane*size.
// size=16 (dwordx4): one instruction gathers 1KB -> 4x256B rows or 8x128B rows.
__device__ __forceinline__ void gld_lds16(const void* g, void* l) {
    __builtin_amdgcn_global_load_lds((const AS1 unsigned int*)g,
                                     (AS3 unsigned int*)l, 16, 0, 0);
}
__device__ __forceinline__ void vm_wait0() {
    asm volatile("s_waitcnt vmcnt(0)" ::: "memory");
}

// bf16 helpers (RNE)
__device__ inline unsigned short f2bf(float x) {
    union { float f; unsigned int u; } v; v.f = x;
    unsigned int r = v.u + 0x7FFF + ((v.u >> 16) & 1);
    return (unsigned short)(r >> 16);
}
__device__ inline float bf2f(unsigned short b) {
    union { float f; unsigned int u; } v; v.u = ((unsigned int)b) << 16;
    return v.f;
}

// ---------------- workspace layout (bytes) ----------------
//   cnt    : 0        uint[50000] (out_deg<<16 | in_deg; written by poolcount)
//   pcnt_s : 200704   uint[196]+pad (zeroed by prep)
//   pcnt_d : 201728   uint[196]+pad (zeroed by prep)
//   routf  : 202752   f32[50000] rsqrt(out_deg) (written by poolcount)
//   bucketu: 403456   ushort[50000*64]   6.4 MB
//   -- overlay zone (dead before spmm1): --
//   pbuf_s : 6803456  uchar[196*4608]    903 KB
//   pbuf_d : 7706624  uint[196*4608]     3.6 MB
//   Ep     : 11319296 ushort[32000*128]  8.2 MB
//   h1     : 6803456  ushort[50000*128] 12.8 MB  (OVERLAYS pbuf_s+pbuf_d+Ep)
//   -- end overlay --
//   G1     : 19603456 ushort[50000*128] 12.8 MB  (UNSCALED pooled E')
//   G2     : 32403456 ushort[50000*64]   6.4 MB
//   W1p    : 38803456 ushort[128*128]    32 KB
//   W2p    : 38836224 ushort[12*512]     12 KB

// ===== prep: zero both pcnt arrays ∥ pack W1 ∥ pack W2 (MFMA B-frag).
__global__ __launch_bounds__(256) void prep_kernel(
        int4* __restrict__ pcnt_zero, const float* __restrict__ W1,
        unsigned short* __restrict__ W1p, const float* __restrict__ W2,
        unsigned short* __restrict__ W2p) {
    int b = blockIdx.x;
    int t = threadIdx.x;
    if (b == 0) {
        if (t < 128) pcnt_zero[t] = make_int4(0, 0, 0, 0);  // 2048 B = both pcnts
    } else if (b < 65) {
        int i = (b - 1) * 256 + t;  // exactly 16384
        int tile = i >> 9, rem = i & 511;
        int ln = rem >> 3, j = rem & 7;
        int nt = tile >> 2, kb = tile & 3;
        int k = kb * 32 + ((ln >> 4) << 3) + j;
        int n = nt * 16 + (ln & 15);
        W1p[i] = f2bf(W1[k * 128 + n]);
    } else {
        int i = (b - 65) * 256 + t;  // exactly 6144
        int tile = i >> 9, rem = i & 511;
        int ln = rem >> 3, j = rem & 7;
        int nt = tile >> 2, kb = tile & 3;      // nt 0..2
        int k = kb * 32 + ((ln >> 4) << 3) + j;
        int n = nt * 16 + (ln & 15);            // 0..47
        W2p[i] = (n < N_CLASSES) ? f2bf(W2[k * N_CLASSES + n]) : (unsigned short)0;
    }
}

// ===== fused: src-scatter ∥ dst-scatter ∥ egemm (scatter hides under MFMA).
__global__ __launch_bounds__(256) void egemm_scat_kernel(
        const int* __restrict__ src, const int* __restrict__ dst,
        unsigned int* __restrict__ pcnt_s, unsigned char* __restrict__ pbuf_s,
        unsigned int* __restrict__ pcnt_d, unsigned int* __restrict__ pbuf_d,
        const float* __restrict__ emb, const unsigned short* __restrict__ W1p,
        unsigned short* __restrict__ Ep) {
    __shared__ unsigned int shm[512];
    int b = blockIdx.x;
    int t = threadIdx.x;
    if (b < 196) {
        // ---- src scatter: partition src ids by u>>8, 1-byte payload (u&255)
        unsigned int* lhist = shm;
        unsigned int* lbase = shm + 256;
        for (int i = t; i < NPART; i += 256) lhist[i] = 0u;
        __syncthreads();
        int base = b * 4096;
        int pid[16]; unsigned int rank[16]; unsigned char val[16];
        #pragma unroll
        for (int k = 0; k < 16; ++k) {
            int i = base + k * 256 + t;
            pid[k] = -1;
            if (i < N_EDGES) {
                int u = src[i];
                val[k] = (unsigned char)(u & 255);
                pid[k] = u >> 8;
                rank[k] = atomicAdd(&lhist[pid[k]], 1u);
            }
        }
        __syncthreads();
        for (int i = t; i < NPART; i += 256)
            lbase[i] = atomicAdd(&pcnt_s[i], lhist[i]);
        __syncthreads();
        #pragma unroll
        for (int k = 0; k < 16; ++k) {
            if (pid[k] >= 0) {
                unsigned int pos = lbase[pid[k]] + rank[k];
                if (pos < PCAP) pbuf_s[pid[k] * PCAP + pos] = val[k];
            }
        }
    } else if (b < 392) {
        // ---- dst scatter: partition by dst>>8, payload (src<<8)|(dst&255)
        unsigned int* lhist = shm;
        unsigned int* lbase = shm + 256;
        for (int i = t; i < NPART; i += 256) lhist[i] = 0u;
        __syncthreads();
        int base = (b - 196) * 4096;
        int pid[16]; unsigned int rank[16]; unsigned int val[16];
        #pragma unroll
        for (int k = 0; k < 16; ++k) {
            int i = base + k * 256 + t;
            pid[k] = -1;
            if (i < N_EDGES) {
                int u = src[i];
                int d = dst[i];
                val[k] = ((unsigned int)u << 8) | (unsigned int)(d & 255);
                pid[k] = d >> 8;
                rank[k] = atomicAdd(&lhist[pid[k]], 1u);
            }
        }
        __syncthreads();
        for (int i = t; i < NPART; i += 256)
            lbase[i] = atomicAdd(&pcnt_d[i], lhist[i]);
        __syncthreads();
        #pragma unroll
        for (int k = 0; k < 16; ++k) {
            if (pid[k] >= 0) {
                unsigned int pos = lbase[pid[k]] + rank[k];
                if (pos < PCAP) pbuf_d[pid[k] * PCAP + pos] = val[k];
            }
        }
    } else {
        // ---- egemm: E' = emb @ W1 via MFMA (rows (b-392)*64 .. +63)
        const int wave = t >> 6, lane = t & 63;
        const int quad = lane >> 4, m = lane & 15;
        const int row0 = (b - 392) * 64 + wave * 16;
        const int arow = row0 + m;                       // < 32000 always
        const float4* ap = (const float4*)(emb + arow * 128 + quad * 8);
        bf16x8 a[4];
        #pragma unroll
        for (int kb = 0; kb < 4; ++kb) {
            float4 x = ap[kb * 8];
            float4 y = ap[kb * 8 + 1];
            bf16x8 tt;
            tt[0] = f2bf(x.x); tt[1] = f2bf(x.y); tt[2] = f2bf(x.z); tt[3] = f2bf(x.w);
            tt[4] = f2bf(y.x); tt[5] = f2bf(y.y); tt[6] = f2bf(y.z); tt[7] = f2bf(y.w);
            a[kb] = tt;
        }
        const int rbase = row0 + quad * 4;
        #pragma unroll
        for (int nt = 0; nt < 8; ++nt) {
            const unsigned short* wp = W1p + (nt * 4) * 512 + lane * 8;
            bf16x8 b0 = *(const bf16x8*)(wp + 0 * 512);
            bf16x8 b1 = *(const bf16x8*)(wp + 1 * 512);
            bf16x8 b2 = *(const bf16x8*)(wp + 2 * 512);
            bf16x8 b3 = *(const bf16x8*)(wp + 3 * 512);
            f32x4 acc = {0.f, 0.f, 0.f, 0.f};
            acc = __builtin_amdgcn_mfma_f32_16x16x32_bf16(a[0], b0, acc, 0, 0, 0);
            acc = __builtin_amdgcn_mfma_f32_16x16x32_bf16(a[1], b1, acc, 0, 0, 0);
            acc = __builtin_amdgcn_mfma_f32_16x16x32_bf16(a[2], b2, acc, 0, 0, 0);
            acc = __builtin_amdgcn_mfma_f32_16x16x32_bf16(a[3], b3, acc, 0, 0, 0);
            #pragma unroll
            for (int r = 0; r < 4; ++r)
                Ep[(rbase + r) * 128 + nt * 16 + m] = f2bf(acc[r]);
        }
    }
}

// ===== R20 poolcount: blocks 0-195 = count (both histograms + buckets,
// LDS-rank, plain stores, zero global atomics); blocks 196.. = pool writing
// UNSCALED G1 = sum/nz (no routf dependency -> count hides under pool).
__global__ __launch_bounds__(256) void poolcount_kernel(
        const unsigned int* __restrict__ pcnt_s, const unsigned char* __restrict__ pbuf_s,
        const unsigned int* __restrict__ pcnt_d, const unsigned int* __restrict__ pbuf_d,
        unsigned int* __restrict__ cnt, float* __restrict__ routf,
        unsigned short* __restrict__ bucketu,
        const int* __restrict__ feats, const unsigned short* __restrict__ Ep,
        unsigned short* __restrict__ G1) {
    __shared__ unsigned int shm[4][SEQ_LEN][64];   // 20 KB (count uses 512 uints)
    __shared__ int tokl[4][SEQ_LEN];
    int b = blockIdx.x;
    int t = threadIdx.x;
    if (b < NPART) {
        // ---- count role (exclusive 256-node ownership per partition)
        unsigned int* ho = &shm[0][0][0];
        unsigned int* hi_ = &shm[0][0][0] + 256;
        ho[t] = 0u;
        hi_[t] = 0u;
        __syncthreads();
        int p = b;
        int ns = min((int)pcnt_s[p], PCAP);
        const unsigned char* ps = pbuf_s + p * PCAP;
        for (int i = t; i < ns; i += 256) atomicAdd(&ho[ps[i]], 1u);
        int nd = min((int)pcnt_d[p], PCAP);
        const unsigned int* pd = pbuf_d + p * PCAP;
        for (int i = t; i < nd; i += 256) {
            unsigned int e = pd[i];
            unsigned int d = e & 255u;
            unsigned int slot = atomicAdd(&hi_[d], 1u);
            if (slot < BUCKET_CAP)
                bucketu[(p * 256 + (int)d) * BUCKET_CAP + slot] = (unsigned short)(e >> 8);
        }
        __syncthreads();
        int v = p * 256 + t;
        if (v < N_NODES) {
            cnt[v] = (ho[t] << 16) | (hi_[t] & 0xffffu);
            routf[v] = rsqrtf(fmaxf((float)ho[t], 1.f));
        }
        return;
    }
    // ---- pool role: 4 nodes/block, 5 size=16 gather instructions/node
    int w = t >> 6, lane = t & 63;
    int v = (b - NPART) * 4 + w;
    int mytok = 0;
    if (lane < SEQ_LEN) {
        mytok = feats[v * SEQ_LEN + lane];
        tokl[w][lane] = mytok;
    }
    int nz = (int)__popcll(__ballot(lane < SEQ_LEN && mytok != 0));
    __syncthreads();
    #pragma unroll
    for (int g = 0; g < SEQ_LEN / 4; ++g) {
        int tok = tokl[w][4 * g + (lane >> 4)];
        gld_lds16(Ep + tok * 128 + (lane & 15) * 8, &shm[w][4 * g][0]);
    }
    vm_wait0();
    float a0 = 0.f, a1 = 0.f;
    #pragma unroll
    for (int s = 0; s < SEQ_LEN; ++s) {
        unsigned int x = shm[w][s][lane];
        a0 += bf2f((unsigned short)(x & 0xffffu));
        a1 += bf2f((unsigned short)(x >> 16));
    }
    float sc = 1.f / (float)max(nz, 1);    // UNSCALED (rout applied in spmm1)
    ushort2 o = {f2bf(a0 * sc), f2bf(a1 * sc)};
    ((ushort2*)G1)[v * 64 + lane] = o;
}

// ===== spmm1: gather+aggregate with per-edge rout -> h1. R20: 16-row
// batches (16.5 KB LDS -> 8 blocks/CU = 32 waves, 2x the latency hiding);
// routf[u] broadcast loads issued before the wait (latency-hidden).
__global__ __launch_bounds__(256) void spmm1_kernel(
        const unsigned int* __restrict__ cnt, const float* __restrict__ routf,
        const unsigned short* __restrict__ bucketu, const unsigned short* __restrict__ G,
        const float* __restrict__ b1, unsigned short* __restrict__ h1) {
    __shared__ unsigned short idxs[256];
    __shared__ unsigned int stg[4][16][64];    // 16 KB gather stage
    int t = threadIdx.x;
    int node = t >> 6, lane = t & 63;
    int v = blockIdx.x * 4 + node;
    idxs[t] = bucketu[blockIdx.x * 256 + t];   // wave-local slice
    int ind = (int)(cnt[v] & 0xffffu);
    float rovv = routf[v];
    float2 bb = ((const float2*)b1)[lane];
    int n = min(ind, BUCKET_CAP);
    const unsigned short* bk = &idxs[node * 64];
    float a0 = 0.f, a1 = 0.f;
    for (int base = 0; base < n; base += 16) {
        int m = min(16, n - base);
        int nin = (m + 3) >> 2;
        for (int g = 0; g < nin; ++g) {
            int rc = min(base + 4 * g + (lane >> 4), n - 1);  // clamp partials
            int u = bk[rc];
            gld_lds16(G + u * 128 + (lane & 15) * 8, &stg[node][4 * g][0]);
        }
        // per-edge rout: 16 independent broadcast loads, overlap gld latency
        float rv[16];
        #pragma unroll
        for (int j = 0; j < 16; ++j)
            rv[j] = routf[bk[base + min(j, m - 1)]];
        vm_wait0();
        #pragma unroll
        for (int j = 0; j < 16; ++j) {
            if (j < m) {
                unsigned int x = stg[node][j][lane];
                a0 += bf2f((unsigned short)(x & 0xffffu)) * rv[j];
                a1 += bf2f((unsigned short)(x >> 16)) * rv[j];
            }
        }
    }
    float rin = rsqrtf(fmaxf((float)ind, 1.f));
    float v0 = fmaxf(a0 * rin + bb.x, 0.f) * rovv;
    float v1 = fmaxf(a1 * rin + bb.y, 0.f) * rovv;
    ushort2 o = {f2bf(v0), f2bf(v1)};
    ((ushort2*)h1)[v * 64 + lane] = o;
}

// ===== gemm2: G2 = h1 @ W2 via MFMA (50048x128 @ 128x48, cols>=40 masked).
__global__ __launch_bounds__(256) void gemm2_kernel(
        const unsigned short* __restrict__ h1, const unsigned short* __restrict__ W2p,
        unsigned short* __restrict__ G2) {
    const int wave = threadIdx.x >> 6, lane = threadIdx.x & 63;
    const int quad = lane >> 4, m = lane & 15;
    const int row0 = blockIdx.x * 64 + wave * 16;
    const int arow = min(row0 + m, N_NODES - 1);
    const unsigned short* ap = h1 + arow * 128 + quad * 8;
    bf16x8 a0 = *(const bf16x8*)(ap + 0);
    bf16x8 a1 = *(const bf16x8*)(ap + 32);
    bf16x8 a2 = *(const bf16x8*)(ap + 64);
    bf16x8 a3 = *(const bf16x8*)(ap + 96);
    const int rbase = row0 + quad * 4;
    #pragma unroll
    for (int nt = 0; nt < 3; ++nt) {
        const unsigned short* wp = W2p + (nt * 4) * 512 + lane * 8;
        bf16x8 b0 = *(const bf16x8*)(wp + 0 * 512);
        bf16x8 b1 = *(const bf16x8*)(wp + 1 * 512);
        bf16x8 b2 = *(const bf16x8*)(wp + 2 * 512);
        bf16x8 b3 = *(const bf16x8*)(wp + 3 * 512);
        f32x4 acc = {0.f, 0.f, 0.f, 0.f};
        acc = __builtin_amdgcn_mfma_f32_16x16x32_bf16(a0, b0, acc, 0, 0, 0);
        acc = __builtin_amdgcn_mfma_f32_16x16x32_bf16(a1, b1, acc, 0, 0, 0);
        acc = __builtin_amdgcn_mfma_f32_16x16x32_bf16(a2, b2, acc, 0, 0, 0);
        acc = __builtin_amdgcn_mfma_f32_16x16x32_bf16(a3, b3, acc, 0, 0, 0);
        int col = nt * 16 + m;
        #pragma unroll
        for (int r = 0; r < 4; ++r) {
            int row = rbase + r;
            if (row < N_NODES && col < N_CLASSES)
                G2[row * 64 + col] = f2bf(acc[r]);
        }
    }
}

// ===== spmm2: layer-2 aggregate + epilogue (8 rows per gld instruction).
__global__ __launch_bounds__(256) void spmm2_kernel(
        const unsigned int* __restrict__ cnt, const unsigned short* __restrict__ bucketu,
        const unsigned short* __restrict__ G2, const float* __restrict__ b2,
        float* __restrict__ out) {
    __shared__ unsigned short idxs[256];
    __shared__ unsigned short stg[4][32][64];  // 16 KB; row stride 128B
    int t = threadIdx.x;
    int node = t >> 6, f = t & 63;
    int v = blockIdx.x * 4 + node;
    idxs[t] = bucketu[blockIdx.x * 256 + t];
    int ind = (int)(cnt[v] & 0xffffu);
    int n = min(ind, BUCKET_CAP);
    float acc = 0.f;
    for (int base = 0; base < n; base += 32) {
        int m = min(32, n - base);
        int nin = (m + 7) >> 3;
        for (int g = 0; g < nin; ++g) {
            int rc = min(base + 8 * g + (f >> 3), n - 1);   // clamp partials
            int u = idxs[node * 64 + rc];
            gld_lds16(G2 + u * 64 + (f & 7) * 8, &stg[node][8 * g][0]);
        }
        vm_wait0();
        if (f < N_CLASSES) {
            #pragma unroll 4
            for (int j = 0; j < m; ++j) acc += bf2f(stg[node][j][f]);
        }
    }
    if (f < N_CLASSES) {
        float rin = rsqrtf(fmaxf((float)ind, 1.f));
        out[v * N_CLASSES + f] = acc * rin + b2[f];
    }
}

extern "C" void kernel_launch(void* const* d_in, const int* in_sizes, int n_in,
                              void* d_out, int out_size, void* d_ws, size_t ws_size,
                              hipStream_t stream) {
    const int*   feats = (const int*)d_in[0];
    const int*   src   = (const int*)d_in[1];
    const int*   dst   = (const int*)d_in[2];
    const float* emb   = (const float*)d_in[3];
    const float* W1    = (const float*)d_in[4];
    const float* b1    = (const float*)d_in[5];
    const float* W2    = (const float*)d_in[6];
    const float* b2    = (const float*)d_in[7];
    float* out = (float*)d_out;

    char* w = (char*)d_ws;
    unsigned int*   cnt     = (unsigned int*)(w + 0);
    unsigned int*   pcnt_s  = (unsigned int*)(w + 200704);
    unsigned int*   pcnt_d  = (unsigned int*)(w + 201728);
    float*          routf   = (float*)(w + 202752);
    unsigned short* bucketu = (unsigned short*)(w + 403456);
    unsigned char*  pbuf_s  = (unsigned char*)(w + 6803456);
    unsigned int*   pbuf_d  = (unsigned int*)(w + 7706624);
    unsigned short* Ep      = (unsigned short*)(w + 11319296);
    unsigned short* h1      = (unsigned short*)(w + 6803456);   // overlay (dead zone)
    unsigned short* G1      = (unsigned short*)(w + 19603456);
    unsigned short* G2      = (unsigned short*)(w + 32403456);
    unsigned short* W1p     = (unsigned short*)(w + 38803456);
    unsigned short* W2p     = (unsigned short*)(w + 38836224);

    // 1) prep: zero pcnts ∥ pack W1 ∥ pack W2
    prep_kernel<<<PREP_BLOCKS, 256, 0, stream>>>((int4*)pcnt_s, W1, W1p, W2, W2p);
    // 2) src/dst scatter ∥ egemm
    egemm_scat_kernel<<<EGS_BLOCKS, 256, 0, stream>>>(
        src, dst, pcnt_s, pbuf_s, pcnt_d, pbuf_d, emb, W1p, Ep);
    // 3) count (196 blocks, hidden) ∥ pool -> unscaled G1
    poolcount_kernel<<<POOLCOUNT_BLOCKS, 256, 0, stream>>>(
        pcnt_s, pbuf_s, pcnt_d, pbuf_d, cnt, routf, bucketu, feats, Ep, G1);
    // 4) spmm1 (per-edge rout) -> h1
    spmm1_kernel<<<POOL_BLOCKS, 256, 0, stream>>>(cnt, routf, bucketu, G1, b1, h1);
    // 5) G2 = h1 @ W2 via MFMA
    gemm2_kernel<<<GEMM2_BLOCKS, 256, 0, stream>>>(h1, W2p, G2);
    // 6) out = agg(G2)*rin + b2
    spmm2_kernel<<<POOL_BLOCKS, 256, 0, stream>>>(cnt, bucketu, G2, b2, out);
}